// Round 8
// baseline (599.976 us; speedup 1.0000x reference)
//
#include <hip/hip_runtime.h>
#include <cstddef>

// Problem constants
#define B_SZ     2
#define L_SEQ    8192
#define D_INNERC 1024
#define D_CAT    2048         // concat of fwd|rev y halves
#define NHEADSC  16
#define CHUNKC   64
#define NCHUNKC  128          // L_SEQ / CHUNK
#define CONV_DIMC 1280
#define D_PROJC  2320
#define M_ROWS   16384        // B_SZ * L_SEQ

typedef unsigned short bfu;   // raw bf16 bits

using bf16x8 = __attribute__((ext_vector_type(8))) short;
using f32x4  = __attribute__((ext_vector_type(4))) float;

__device__ __forceinline__ float silu_(float v) { return v / (1.f + expf(-v)); }

__device__ __forceinline__ float b2f(bfu u) {
  return __uint_as_float((unsigned)u << 16);
}
__device__ __forceinline__ bfu f2b(float f) {
  unsigned x = __float_as_uint(f);
  return (bfu)((x + 0x7fffu + ((x >> 16) & 1u)) >> 16);   // RNE
}

__device__ __forceinline__ float4 ld4(const float* p) { return *(const float4*)p; }
__device__ __forceinline__ float4 ld4(const bfu* p) {
  ushort4 u = *(const ushort4*)p;
  float4 f;
  f.x = b2f(u.x); f.y = b2f(u.y); f.z = b2f(u.z); f.w = b2f(u.w);
  return f;
}
__device__ __forceinline__ void st4(float* p, float4 v) { *(float4*)p = v; }
__device__ __forceinline__ void st4(bfu* p, float4 v) {
  ushort4 u;
  u.x = f2b(v.x); u.y = f2b(v.y); u.z = f2b(v.z); u.w = f2b(v.w);
  *(ushort4*)p = u;
}

__device__ __forceinline__ void gl_lds16(const bfu* g, bfu* l) {
  __builtin_amdgcn_global_load_lds(
      (const __attribute__((address_space(1))) unsigned int*)g,
      (__attribute__((address_space(3))) unsigned int*)l, 16, 0, 0);
}

__device__ __forceinline__ int pos_of(int b, int c, int l, int dir) {
  int t = c * CHUNKC + l;
  return dir ? (b * L_SEQ + (L_SEQ - 1) - t) : (b * L_SEQ + t);
}

// ---------------------------------------------------------------------------
// MFMA GEMM (NT): C[m][n] = sum_k A[m][k] * Bw[n][k].  A,B bf16, K-contig.
// 128x128 tile, BK=64 (K % 64 == 0), 256 thr = 4 waves 2x2, 4x4x(2 k-step)
// MFMAs of 16x16x32.  mode: 0 -> store bf16;  1 -> store f32 (+bias)
// ---------------------------------------------------------------------------
__global__ __launch_bounds__(256)
void mfma_nt(const bfu* __restrict__ A, int lda,
             const bfu* __restrict__ Bw, int ldb,
             void* __restrict__ Cv, int ldc,
             int N, int K, const float* __restrict__ bias, int mode)
{
  __shared__ bfu sh[16384];           // 32 KB: As | Bs, reused by epilogue
  bfu* As = sh;                       // 128 x 64
  bfu* Bs = sh + 8192;                // 128 x 64
  const int tid  = threadIdx.x;
  const int lane = tid & 63;
  const int wave = __builtin_amdgcn_readfirstlane(tid >> 6);
  const int wm = wave & 1, wn = wave >> 1;

  const int num_n = gridDim.x;
  const int flat  = blockIdx.y * num_n + blockIdx.x;
  const int xcd   = flat & 7;
  const int g     = flat >> 3;
  const int n0 = (g % num_n) * 128;
  const int m0 = ((g / num_n) * 8 + xcd) * 128;

  f32x4 acc[4][4];
#pragma unroll
  for (int i = 0; i < 4; ++i)
#pragma unroll
    for (int j = 0; j < 4; ++j)
      acc[i][j] = (f32x4){0.f, 0.f, 0.f, 0.f};

  const int ro   = lane >> 3;          // row within 8-row staging slice
  const int slot = lane & 7;           // stored colgroup slot

  for (int k0 = 0; k0 < K; k0 += 64) {
    __syncthreads();
    // each wave stages rows [wave*32, wave*32+32) of A and B, 8 rows/call
#pragma unroll
    for (int si = 0; si < 4; ++si) {
      int r = wave * 32 + si * 8 + ro;
      int cg = slot ^ (r & 7);
      gl_lds16(A  + (size_t)(m0 + r) * lda + k0 + cg * 8, As + (wave * 32 + si * 8) * 64);
      gl_lds16(Bw + (size_t)(n0 + r) * ldb + k0 + cg * 8, Bs + (wave * 32 + si * 8) * 64);
    }
    __syncthreads();

#pragma unroll
    for (int ks = 0; ks < 2; ++ks) {
      bf16x8 af[4], bfr[4];
#pragma unroll
      for (int i = 0; i < 4; ++i) {
        int ra = wm * 64 + i * 16 + (lane & 15);
        int ca = (ks * 4 + (lane >> 4)) ^ (ra & 7);
        af[i] = *(const bf16x8*)(As + ra * 64 + ca * 8);
        int rb = wn * 64 + i * 16 + (lane & 15);
        int cb = (ks * 4 + (lane >> 4)) ^ (rb & 7);
        bfr[i] = *(const bf16x8*)(Bs + rb * 64 + cb * 8);
      }
#pragma unroll
      for (int i = 0; i < 4; ++i)
#pragma unroll
        for (int j = 0; j < 4; ++j)
          acc[i][j] = __builtin_amdgcn_mfma_f32_16x16x32_bf16(af[i], bfr[j], acc[i][j], 0, 0, 0);
    }
  }

  // ---- epilogue: repack through LDS, coalesced dwordx4 stores ----
  // C/D layout: col = lane&15, row = (lane>>4)*4 + reg
  __syncthreads();
  if (mode == 0) {
    // whole 128x128 bf16 tile fits in 32 KB
#pragma unroll
    for (int i = 0; i < 4; ++i)
#pragma unroll
      for (int j = 0; j < 4; ++j)
#pragma unroll
        for (int r = 0; r < 4; ++r) {
          int ml = wm * 64 + i * 16 + (lane >> 4) * 4 + r;
          int nl = wn * 64 + j * 16 + (lane & 15);
          sh[ml * 128 + nl] = f2b(acc[i][j][r]);
        }
    __syncthreads();
    bfu* Cb = (bfu*)Cv;
#pragma unroll
    for (int rr = 0; rr < 8; ++rr) {
      int idx = rr * 256 + tid;            // 8-elem group id, 0..2047
      int row = idx >> 4, co = (idx & 15) * 8;
      if (n0 + co < N) {                   // N is 8-aligned
        *(ulonglong2*)(Cb + (size_t)(m0 + row) * ldc + n0 + co) =
            *(const ulonglong2*)(sh + row * 128 + co);
      }
    }
  } else {
    float* Cf = (float*)Cv;
    float* shf = (float*)sh;               // 64 rows x 128 f32 per pass
#pragma unroll
    for (int p = 0; p < 2; ++p) {
      if (wm == p) {
#pragma unroll
        for (int i = 0; i < 4; ++i)
#pragma unroll
          for (int j = 0; j < 4; ++j)
#pragma unroll
            for (int r = 0; r < 4; ++r) {
              int ml = i * 16 + (lane >> 4) * 4 + r;   // 0..63
              int nl = wn * 64 + j * 16 + (lane & 15);
              shf[ml * 128 + nl] = acc[i][j][r];
            }
      }
      __syncthreads();
#pragma unroll
      for (int rr = 0; rr < 8; ++rr) {
        int idx = rr * 256 + tid;          // float4 group id, 0..2047
        int row = idx >> 5, co = (idx & 31) * 4;
        int n = n0 + co;
        if (n < N) {
          float4 v = *(float4*)(shf + row * 128 + co);
          float* cp = Cf + (size_t)(m0 + p * 64 + row) * ldc + n;
          if (bias) {
            v.x += bias[n]; v.y += bias[n + 1]; v.z += bias[n + 2]; v.w += bias[n + 3];
          }
          *(float4*)cp = v;
        }
      }
      __syncthreads();
    }
  }
}

// ---------------------------------------------------------------------------
// 8-phase 256x256 MFMA GEMM (NT), bf16 out.  512 thr = 8 waves (2M x 4N),
// BK=64, K % 128 == 0, M % 256 == 0.  LDS 128 KB: double-buffered A,B tiles.
// Counted vmcnt(4) at phases 4 and 8 only (never 0 mid-loop).
// ---------------------------------------------------------------------------
__global__ __launch_bounds__(512)
void mfma_nt_8p(const bfu* __restrict__ A, int lda,
                const bfu* __restrict__ Bw, int ldb,
                bfu* __restrict__ C, int ldc, int N, int K)
{
  __shared__ bfu sh[65536];            // 128 KB; reused by epilogue (256x256)
  bfu* As0 = sh;                        // tile kt   (even), A 256x64
  bfu* As1 = sh + 16384;                // tile kt+1 (odd),  A 256x64
  bfu* Bs0 = sh + 32768;                // tile kt   B 256x64
  bfu* Bs1 = sh + 49152;                // tile kt+1 B 256x64

  const int tid  = threadIdx.x;
  const int lane = tid & 63;
  const int w    = __builtin_amdgcn_readfirstlane(tid >> 6);
  const int wm = w & 1, wn = w >> 1;    // 2 x 4 wave grid
  const int q = lane >> 4, t = lane & 15;

  const int num_n = gridDim.x;
  const int flat  = blockIdx.y * num_n + blockIdx.x;
  const int xcd   = flat & 7;
  const int g     = flat >> 3;
  const int n0 = (g % num_n) * 256;
  const int m0 = ((g / num_n) * 8 + xcd) * 256;

  auto STG = [&](const bfu* __restrict__ X, int ldx, int x0, int kt, int h,
                 bfu* dst) {
#pragma unroll
    for (int ci = 0; ci < 2; ++ci) {
      int rb = h * 128 + ci * 64 + w * 8;          // wave-uniform row base
      int r  = rb + (lane >> 3);
      int cg = (lane & 7) ^ (r & 7);
      gl_lds16(X + (size_t)(x0 + r) * ldx + kt * 64 + cg * 8, dst + rb * 64);
    }
  };
  auto FR = [&](const bfu* tile, int R, int gg) -> bf16x8 {
    return *(const bf16x8*)(tile + R * 64 + ((gg ^ (R & 7)) * 8));
  };

  f32x4 acc[8][4];
#pragma unroll
  for (int i = 0; i < 8; ++i)
#pragma unroll
    for (int j = 0; j < 4; ++j)
      acc[i][j] = (f32x4){0.f, 0.f, 0.f, 0.f};

  // prologue: tile0 (B,A) + tile1 B; tile1 A is staged in iter0 p0/p1
  STG(Bw, ldb, n0, 0, 0, Bs0); STG(Bw, ldb, n0, 0, 1, Bs0);
  STG(A,  lda, m0, 0, 0, As0); STG(A,  lda, m0, 0, 1, As0);
  STG(Bw, ldb, n0, 1, 0, Bs1); STG(Bw, ldb, n0, 1, 1, Bs1);
  asm volatile("s_waitcnt vmcnt(4)" ::: "memory");   // tile0 landed
  __builtin_amdgcn_s_barrier();

  const int nIter = K >> 7;            // K % 128 == 0
  bf16x8 bfr[4][2];
  for (int it = 0; it < nIter; ++it) {
    const int kt = it * 2;
    const bool last = (it == nIter - 1);

    // ---- K-tile kt (As0/Bs0), phases 0..3 ----
#pragma unroll
    for (int p = 0; p < 4; ++p) {
      bf16x8 af[2][2];
#pragma unroll
      for (int ii = 0; ii < 2; ++ii)
#pragma unroll
        for (int ks = 0; ks < 2; ++ks)
          af[ii][ks] = FR(As0, wm * 128 + (2 * p + ii) * 16 + t, ks * 4 + q);
      if (p == 0) {
#pragma unroll
        for (int j = 0; j < 4; ++j)
#pragma unroll
          for (int ks = 0; ks < 2; ++ks)
            bfr[j][ks] = FR(Bs0, wn * 64 + j * 16 + t, ks * 4 + q);
      }
      if (p == 0)          STG(A,  lda, m0, kt + 1, 0, As1);
      if (p == 1)          STG(A,  lda, m0, kt + 1, 1, As1);
      if (p == 2 && !last) STG(Bw, ldb, n0, kt + 2, 0, Bs0);
      if (p == 3 && !last) STG(Bw, ldb, n0, kt + 2, 1, Bs0);
      if (p == 3) {
        if (last) asm volatile("s_waitcnt vmcnt(0)" ::: "memory");
        else      asm volatile("s_waitcnt vmcnt(4)" ::: "memory");
      }
      __builtin_amdgcn_s_barrier();
      __builtin_amdgcn_s_setprio(1);
#pragma unroll
      for (int ks = 0; ks < 2; ++ks)
#pragma unroll
        for (int ii = 0; ii < 2; ++ii)
#pragma unroll
          for (int j = 0; j < 4; ++j)
            acc[2 * p + ii][j] = __builtin_amdgcn_mfma_f32_16x16x32_bf16(
                af[ii][ks], bfr[j][ks], acc[2 * p + ii][j], 0, 0, 0);
      __builtin_amdgcn_s_setprio(0);
      __builtin_amdgcn_s_barrier();
    }

    // ---- K-tile kt+1 (As1/Bs1), phases 4..7 ----
#pragma unroll
    for (int p = 0; p < 4; ++p) {
      bf16x8 af[2][2];
#pragma unroll
      for (int ii = 0; ii < 2; ++ii)
#pragma unroll
        for (int ks = 0; ks < 2; ++ks)
          af[ii][ks] = FR(As1, wm * 128 + (2 * p + ii) * 16 + t, ks * 4 + q);
      if (p == 0) {
#pragma unroll
        for (int j = 0; j < 4; ++j)
#pragma unroll
          for (int ks = 0; ks < 2; ++ks)
            bfr[j][ks] = FR(Bs1, wn * 64 + j * 16 + t, ks * 4 + q);
      }
      if (p == 0 && !last) STG(A,  lda, m0, kt + 2, 0, As0);
      if (p == 1 && !last) STG(A,  lda, m0, kt + 2, 1, As0);
      if (p == 2 && !last) STG(Bw, ldb, n0, kt + 3, 0, Bs1);
      if (p == 3 && !last) STG(Bw, ldb, n0, kt + 3, 1, Bs1);
      if (p == 3 && !last) asm volatile("s_waitcnt vmcnt(4)" ::: "memory");
      __builtin_amdgcn_s_barrier();
      __builtin_amdgcn_s_setprio(1);
#pragma unroll
      for (int ks = 0; ks < 2; ++ks)
#pragma unroll
        for (int ii = 0; ii < 2; ++ii)
#pragma unroll
          for (int j = 0; j < 4; ++j)
            acc[2 * p + ii][j] = __builtin_amdgcn_mfma_f32_16x16x32_bf16(
                af[ii][ks], bfr[j][ks], acc[2 * p + ii][j], 0, 0, 0);
      __builtin_amdgcn_s_setprio(0);
      __builtin_amdgcn_s_barrier();
    }
  }

  // ---- epilogue: repack 256x256 bf16 through LDS (exactly 128 KB) ----
#pragma unroll
  for (int i = 0; i < 8; ++i)
#pragma unroll
    for (int j = 0; j < 4; ++j)
#pragma unroll
      for (int r = 0; r < 4; ++r) {
        int ml = wm * 128 + i * 16 + q * 4 + r;
        int nl = wn * 64 + j * 16 + t;
        sh[ml * 256 + nl] = f2b(acc[i][j][r]);
      }
  __syncthreads();
#pragma unroll
  for (int rr = 0; rr < 16; ++rr) {
    int idx = rr * 512 + tid;            // 8-elem group id, 0..8191
    int row = idx >> 5, co = (idx & 31) * 8;
    if (n0 + co < N) {                   // N is 8-aligned
      *(ulonglong2*)(C + (size_t)(m0 + row) * ldc + n0 + co) =
          *(const ulonglong2*)(sh + row * 256 + co);
    }
  }
}

// ---------------------------------------------------------------------------
// setup converts (all fp32 -> bf16)
// ---------------------------------------------------------------------------
__global__ __launch_bounds__(256)
void cvt_x_k(const float* __restrict__ in, bfu* __restrict__ out)
{
  int q = blockIdx.x * 256 + threadIdx.x;
  st4(out + (size_t)q * 4, ld4(in + (size_t)q * 4));
}

__global__ __launch_bounds__(256)
void cvt_w_k(const float* __restrict__ in, bfu* __restrict__ out)
{
  int q = blockIdx.x * 256 + threadIdx.x;
  int row = q >> 7, c4 = (q & 127) << 2;
  float4 v = {0.f, 0.f, 0.f, 0.f};
  if (row < D_PROJC) v = ld4(in + (size_t)row * 512 + c4);
  st4(out + (size_t)row * 512 + c4, v);
}

// ssm_out_w (512 x 1024 f32) -> ssmTb (1024 x 512 bf16)
__global__ __launch_bounds__(256)
void transpose_k(const float* __restrict__ in, bfu* __restrict__ out)
{
  int idx = blockIdx.x * 256 + threadIdx.x;   // 0 .. 524287
  int j = idx >> 9, k = idx & 511;
  out[idx] = f2b(in[k * 1024 + j]);
}

// fuse_w (512 x 1024 f32) -> fuseA (1024 x 512 bf16), row m' = o*2 + dir
__global__ __launch_bounds__(256)
void cvt_fuse_k(const float* __restrict__ in, bfu* __restrict__ out)
{
  int q = blockIdx.x * 256 + threadIdx.x;     // 0 .. 131071 (4-elem groups)
  int m = q >> 7, kg = (q & 127) << 2;        // m' = o*2 + dir
  int o = m >> 1, dir = m & 1;
  float4 v = ld4(in + (size_t)o * 1024 + dir * 512 + kg);
  st4(out + (size_t)m * 512 + kg, v);
}

// ---------------------------------------------------------------------------
// Depthwise conv + bias + SiLU, 8 outputs per thread (taps staged in regs).
// Dir-batched: grid (5, 2048*ndir); blockIdx.y>>11 selects dir slot.
// ---------------------------------------------------------------------------
__global__ __launch_bounds__(256)
void conv_k(const bfu* __restrict__ zx, const float* __restrict__ conv_w,
            const float* __restrict__ conv_b, bfu* __restrict__ xBC,
            size_t xbc_str, int dir_lo)
{
  int di  = blockIdx.y >> 11;
  int dir = dir_lo + di;
  bfu* xBCd = xBC + (size_t)di * xbc_str;
  int ch = blockIdx.x * 256 + threadIdx.x;   // 0..1279
  int m0 = (blockIdx.y & 2047) * 8;          // global row base
  int b  = m0 >> 13, tb = m0 & (L_SEQ - 1);
  float w0 = conv_w[ch * 4 + 0], w1 = conv_w[ch * 4 + 1];
  float w2 = conv_w[ch * 4 + 2], w3 = conv_w[ch * 4 + 3];
  float cb = conv_b[ch];
  const bfu* src = zx + 1024 + ch;
  const int shift = dir ? 0 : 3;

  float v[11];
#pragma unroll
  for (int i = 0; i < 11; ++i) {
    int tt = tb + i - shift;
    v[i] = (tt >= 0 && tt < L_SEQ)
         ? b2f(src[(size_t)(b * L_SEQ + tt) * D_PROJC]) : 0.f;
  }
#pragma unroll
  for (int j = 0; j < 8; ++j) {
    float acc = cb;
    if (dir == 0) {
      acc += w0 * v[j] + w1 * v[j + 1] + w2 * v[j + 2] + w3 * v[j + 3];
    } else {
      acc += w0 * v[j + 3] + w1 * v[j + 2] + w2 * v[j + 1] + w3 * v[j];
    }
    xBCd[(size_t)(m0 + j) * CONV_DIMC + ch] = f2b(silu_(acc));
  }
}

// ---------------------------------------------------------------------------
// MFMA states: per (b,c) block, 8 heads/block.  Dir-batched: grid 512*ndir.
// T14 async-stage: head i+1's xh global loads issued into registers before
// head i's compute; consumed at next xsT write.
// ---------------------------------------------------------------------------
__global__ __launch_bounds__(256)
void states_mfma_k(const bfu* __restrict__ zx, const bfu* __restrict__ xBC,
                   size_t xbc_str,
                   const float* __restrict__ dt_bias, const float* __restrict__ A_log,
                   float* __restrict__ acum_g, float* __restrict__ dt_g,
                   size_t ac_str,
                   bfu* __restrict__ states, size_t st_str, int dir_lo)
{
  __shared__ bfu BT[128 * 72];     // [n][l]
  __shared__ bfu xsT[64 * 72];     // [p][l]
  __shared__ float scaleS[8 * 64];

  int di  = blockIdx.x >> 9;
  int dir = dir_lo + di;
  const bfu* xBCd = xBC + (size_t)di * xbc_str;
  float* acumd = acum_g + (size_t)di * ac_str;
  float* dtgd  = dt_g   + (size_t)di * ac_str;
  bfu* statesd = states + (size_t)di * st_str;

  int bid = blockIdx.x & 511;
  int hb = bid >> 8;
  int c = bid & 127, b = (bid >> 7) & 1;
  int tid = threadIdx.x, lane = tid & 63;
  int w = tid >> 6, q = lane >> 4, t = lane & 15;

#pragma unroll
  for (int rr = 0; rr < 2; ++rr) {
    int i = w + rr * 4;
    int h = hb * 8 + i;
    int l = lane;
    int pos = pos_of(b, c, l, dir);
    float dtr = b2f(zx[(size_t)pos * D_PROJC + 2304 + h]) + dt_bias[h];
    float dt = (dtr > 20.f) ? dtr : log1pf(expf(dtr));
    float a = -expf(A_log[h]) * dt;
#pragma unroll
    for (int off = 1; off < 64; off <<= 1) {
      float v = __shfl_up(a, off);
      if (l >= off) a += v;
    }
    float alast = __shfl(a, 63);
    int gi = ((b * NCHUNKC + c) * NHEADSC + h) * 64 + l;
    acumd[gi] = a; dtgd[gi] = dt;
    scaleS[i * 64 + l] = dt * expf(alast - a);
  }

#pragma unroll
  for (int r = 0; r < 8; ++r) {
    int qq = tid + r * 256;
    int l = qq & 63, ng = qq >> 6;
    ushort4 v = *(const ushort4*)(xBCd + (size_t)pos_of(b, c, l, dir) * CONV_DIMC + 1024 + ng * 4);
    BT[(ng * 4 + 0) * 72 + l] = v.x; BT[(ng * 4 + 1) * 72 + l] = v.y;
    BT[(ng * 4 + 2) * 72 + l] = v.z; BT[(ng * 4 + 3) * 72 + l] = v.w;
  }

  ushort4 xr[4];
  auto PREFX = [&](int i) {
    int h = hb * 8 + i;
#pragma unroll
    for (int r = 0; r < 4; ++r) {
      int qq = tid + r * 256;
      int l = qq & 63, pg = qq >> 6;
      xr[r] = *(const ushort4*)(xBCd + (size_t)pos_of(b, c, l, dir) * CONV_DIMC + h * 64 + pg * 4);
    }
  };
  PREFX(0);
  __syncthreads();

  for (int i = 0; i < 8; ++i) {
    int h = hb * 8 + i;
#pragma unroll
    for (int r = 0; r < 4; ++r) {
      int qq = tid + r * 256;
      int l = qq & 63, pg = qq >> 6;
      float s = scaleS[i * 64 + l];
      ushort4 v = xr[r];
      xsT[(pg * 4 + 0) * 72 + l] = f2b(b2f(v.x) * s);
      xsT[(pg * 4 + 1) * 72 + l] = f2b(b2f(v.y) * s);
      xsT[(pg * 4 + 2) * 72 + l] = f2b(b2f(v.z) * s);
      xsT[(pg * 4 + 3) * 72 + l] = f2b(b2f(v.w) * s);
    }
    if (i < 7) PREFX(i + 1);
    __syncthreads();

    bf16x8 axs[2];
#pragma unroll
    for (int ks = 0; ks < 2; ++ks)
      axs[ks] = *(const bf16x8*)(xsT + (w * 16 + t) * 72 + ks * 32 + q * 8);

    f32x4 acc[8];
#pragma unroll
    for (int j = 0; j < 8; ++j) acc[j] = (f32x4){0.f, 0.f, 0.f, 0.f};
#pragma unroll
    for (int ks = 0; ks < 2; ++ks)
#pragma unroll
      for (int j = 0; j < 8; ++j) {
        bf16x8 bB = *(const bf16x8*)(BT + (j * 16 + t) * 72 + ks * 32 + q * 8);
        acc[j] = __builtin_amdgcn_mfma_f32_16x16x32_bf16(axs[ks], bB, acc[j], 0, 0, 0);
      }

    size_t base = ((size_t)(b * NCHUNKC + c) * NHEADSC + h) * 8192;
#pragma unroll
    for (int j = 0; j < 8; ++j)
#pragma unroll
      for (int r = 0; r < 4; ++r) {
        int p = w * 16 + q * 4 + r, n = j * 16 + t;
        statesd[base + p * 128 + n] = f2b(acc[j][r]);
      }
    __syncthreads();
  }
}

// ---------------------------------------------------------------------------
// Inter-chunk scan with explicit next-chunk prefetch.  Dir-batched:
// grid 512*ndir; (b,h,eb) from low 9 bits.  (Round-3 verified inner loop.)
// ---------------------------------------------------------------------------
__global__ __launch_bounds__(256)
void scan_k(bfu* __restrict__ states, size_t st_str,
            const float* __restrict__ acum_g, size_t ac_str)
{
  int di  = blockIdx.x >> 9;
  int bid = blockIdx.x & 511;
  bfu* statesd = states + (size_t)di * st_str;
  const float* acumd = acum_g + (size_t)di * ac_str;

  int eb = bid & 15, h = (bid >> 4) & 15, b = bid >> 8;
  int e = eb * 512 + threadIdx.x * 2;
  bfu* p0 = statesd + ((size_t)(b * NCHUNKC) * NHEADSC + h) * 8192 + e;
  const float* ac = acumd + ((b * NCHUNKC) * NHEADSC + h) * 64 + 63;
  const size_t cstride = (size_t)NHEADSC * 8192;
  const int astride = NHEADSC * 64;

  float pre0 = 0.f, pre1 = 0.f;
  uint raw = *(const uint*)p0;
  float dcur = expf(ac[0]);
  for (int c = 0; c < NCHUNKC; ++c) {
    uint raw_next = 0; float dnext = 0.f;
    if (c < NCHUNKC - 1) {
      raw_next = *(const uint*)(p0 + (c + 1) * cstride);
      dnext = expf(ac[(c + 1) * astride]);
    }
    float v0 = b2f((bfu)(raw & 0xffff));
    float v1 = b2f((bfu)(raw >> 16));
    uint packed = (uint)f2b(pre0) | ((uint)f2b(pre1) << 16);
    *(uint*)(p0 + c * cstride) = packed;
    pre0 = v0 + dcur * pre0;
    pre1 = v1 + dcur * pre1;
    raw = raw_next; dcur = dnext;
  }
}

// ---------------------------------------------------------------------------
// MFMA Y + fused gating/RMSNorm: per (b,c) block, ALL 16 heads/block
// (grid 256*ndir).  C/B staging + sacc computed ONCE per (b,c) (was 2x).
// Per head: yacc/acc2 as before, then gate with silu(z) (z staged in LDS),
// accumulate per-row sum(g^2) in registers, store bf16(g) to ycat.
// Epilogue: t-group shuffle-reduce -> scale[l] -> coalesced in-kernel
// rescale of the block's own 64x1024 tile (L2-hot) by scale*norm_w.
// Rounding count identical to the old y_mfma+norm_k pair (bf16 store, then
// scale+restore), so absmax is preserved.
// ---------------------------------------------------------------------------
__global__ __launch_bounds__(256)
void y_mfma_k(const bfu* __restrict__ xBC, size_t xbc_str,
              const bfu* __restrict__ states, size_t st_str,
              const float* __restrict__ acum_g, const float* __restrict__ dt_g,
              size_t ac_str, const float* __restrict__ D_skip,
              const bfu* __restrict__ zx, const float* __restrict__ norm_w,
              bfu* __restrict__ ycat, int dir_lo)
{
  __shared__ bfu smem[35712];           // 71424 B total
  bfu* Cs  = smem;                      // 64 x 136
  bfu* Bsc = smem + 8704;               // 64 x 136 (B tile; sc overlays)
  bfu* Ps  = smem + 17408;              // 64 x 136
  bfu* xhT = smem + 26112;              // 64 x 72
  bfu* zs  = smem + 30720;              // 64 x 72 (z tile, row-major)
  float* acumH  = (float*)(smem + 35328);
  float* dtH    = acumH + 64;
  float* scaleL = dtH + 64;             // 64 f32 (needs smem >= 35712 bfu)

  int di  = blockIdx.x >> 8;
  int dir = dir_lo + di;
  const bfu* xBCd = xBC + (size_t)di * xbc_str;
  const bfu* statesd = states + (size_t)di * st_str;
  const float* acumd = acum_g + (size_t)di * ac_str;
  const float* dtgd  = dt_g   + (size_t)di * ac_str;

  int bid = blockIdx.x & 255;
  int c = bid & 127, b = bid >> 7;
  int tid = threadIdx.x, lane = tid & 63;
  int w = tid >> 6, q = lane >> 4, t = lane & 15;

#pragma unroll
  for (int r = 0; r < 8; ++r) {
    int qq = tid + r * 256;
    int row = qq >> 5, grp = qq & 31;
    const bfu* src = xBCd + (size_t)pos_of(b, c, row, dir) * CONV_DIMC;
    *(ushort4*)(Cs  + row * 136 + grp * 4) = *(const ushort4*)(src + 1152 + grp * 4);
    *(ushort4*)(Bsc + row * 136 + grp * 4) = *(const ushort4*)(src + 1024 + grp * 4);
  }
  __syncthreads();

  bf16x8 af[4];
#pragma unroll
  for (int ks = 0; ks < 4; ++ks)
    af[ks] = *(const bf16x8*)(Cs + (w * 16 + t) * 136 + ks * 32 + q * 8);

  f32x4 sacc[4];
#pragma unroll
  for (int j = 0; j < 4; ++j) sacc[j] = (f32x4){0.f, 0.f, 0.f, 0.f};
#pragma unroll
  for (int ks = 0; ks < 4; ++ks)
#pragma unroll
    for (int j = 0; j < 4; ++j) {
      bf16x8 bf = *(const bf16x8*)(Bsc + (j * 16 + t) * 136 + ks * 32 + q * 8);
      sacc[j] = __builtin_amdgcn_mfma_f32_16x16x32_bf16(af[ks], bf, sacc[j], 0, 0, 0);
    }

  float ssp[4] = {0.f, 0.f, 0.f, 0.f};   // per-row (r) sum of g^2

  for (int h = 0; h < NHEADSC; ++h) {
    __syncthreads();
    size_t pbase = ((size_t)(b * NCHUNKC + c) * NHEADSC + h) * 8192;
#pragma unroll
    for (int r = 0; r < 8; ++r) {
      int qq = tid + r * 256;
      int row = qq >> 5, grp = qq & 31;
      *(ushort4*)(Ps + row * 136 + grp * 4) =
          *(const ushort4*)(statesd + pbase + row * 128 + grp * 4);
    }
#pragma unroll
    for (int r = 0; r < 4; ++r) {
      int qq = tid + r * 256;
      int l = qq & 63, pg = qq >> 6;
      ushort4 v = *(const ushort4*)(xBCd + (size_t)pos_of(b, c, l, dir) * CONV_DIMC + h * 64 + pg * 4);
      xhT[(pg * 4 + 0) * 72 + l] = v.x; xhT[(pg * 4 + 1) * 72 + l] = v.y;
      xhT[(pg * 4 + 2) * 72 + l] = v.z; xhT[(pg * 4 + 3) * 72 + l] = v.w;
    }
    // z tile for this head (row-major: zs[l][p]), coalesced ushort4 loads
#pragma unroll
    for (int r = 0; r < 4; ++r) {
      int qq = tid + r * 256;
      int row = qq >> 4, cg = qq & 15;
      *(ushort4*)(zs + row * 72 + cg * 4) =
          *(const ushort4*)(zx + (size_t)pos_of(b, c, row, dir) * D_PROJC + h * 64 + cg * 4);
    }
    if (tid < 64) {
      int gi = ((b * NCHUNKC + c) * NHEADSC + h) * 64 + tid;
      acumH[tid] = acumd[gi]; dtH[tid] = dtgd[gi];
    }
    __syncthreads();

    f32x4 yacc[4];
#pragma unroll
    for (int j = 0; j < 4; ++j) yacc[j] = (f32x4){0.f, 0.f, 0.f, 0.f};
#pragma unroll
    for (int ks = 0; ks < 4; ++ks)
#pragma unroll
      for (int j = 0; j < 4; ++j) {
        bf16x8 bP = *(const bf16x8*)(Ps + (j * 16 + t) * 136 + ks * 32 + q * 8);
        yacc[j] = __builtin_amdgcn_mfma_f32_16x16x32_bf16(af[ks], bP, yacc[j], 0, 0, 0);
      }

    float Dh = D_skip[h];
    bfu* sc = Bsc;
#pragma unroll
    for (int j = 0; j < 4; ++j)
#pragma unroll
      for (int r = 0; r < 4; ++r) {
        int l = w * 16 + q * 4 + r, s = j * 16 + t;
        float v = 0.f;
        if (s <= l) v = sacc[j][r] * expf(acumH[l] - acumH[s]) * dtH[s];
        if (s == l) v += Dh;
        sc[l * 72 + s] = f2b(v);
      }

    f32x4 acc2[4];
    float dec[4];
#pragma unroll
    for (int r = 0; r < 4; ++r) dec[r] = expf(acumH[w * 16 + q * 4 + r]);
#pragma unroll
    for (int j = 0; j < 4; ++j)
#pragma unroll
      for (int r = 0; r < 4; ++r) acc2[j][r] = yacc[j][r] * dec[r];

#pragma unroll
    for (int ks = 0; ks < 2; ++ks) {
      bf16x8 asc = *(const bf16x8*)(sc + (w * 16 + t) * 72 + ks * 32 + q * 8);
#pragma unroll
      for (int j = 0; j < 4; ++j) {
        bf16x8 bx = *(const bf16x8*)(xhT + (j * 16 + t) * 72 + ks * 32 + q * 8);
        acc2[j] = __builtin_amdgcn_mfma_f32_16x16x32_bf16(asc, bx, acc2[j], 0, 0, 0);
      }
    }

    // gate with silu(z), accumulate sum(g^2) per row, store bf16(g)
#pragma unroll
    for (int j = 0; j < 4; ++j)
#pragma unroll
      for (int r = 0; r < 4; ++r) {
        int l = w * 16 + q * 4 + r, p = j * 16 + t;
        float g = acc2[j][r] * silu_(b2f(zs[l * 72 + p]));
        ssp[r] += g * g;
        ycat[(size_t)pos_of(b, c, l, dir) * D_CAT + dir * 1024 + h * 64 + p] =
            f2b(g);
      }
  }

  // ---- RMSNorm epilogue ----
  // reduce ssp over the 16-lane t-group (lanes q*16..q*16+15 of each wave)
#pragma unroll
  for (int r = 0; r < 4; ++r) {
#pragma unroll
    for (int off = 1; off < 16; off <<= 1) ssp[r] += __shfl_xor(ssp[r], off);
  }
  if (t == 0) {
#pragma unroll
    for (int r = 0; r < 4; ++r) {
      int l = w * 16 + q * 4 + r;
      scaleL[l] = rsqrtf(ssp[r] * (1.f / 1024.f) + 1e-5f);
    }
  }
  __threadfence_block();   // make this block's ycat writes visible block-wide
  __syncthreads();

  // coalesced rescale of the block's own 64x1024 tile (L2-hot)
#pragma unroll
  for (int it = 0; it < 32; ++it) {
    int idx = it * 256 + tid;            // 8-elem group id, 0..8191
    int row = idx >> 7, co = (idx & 127) * 8;
    bfu* yp = ycat + (size_t)pos_of(b, c, row, dir) * D_CAT + dir * 1024 + co;
    ushort4 v0 = *(const ushort4*)yp;
    ushort4 v1 = *(const ushort4*)(yp + 4);
    float s = scaleL[row];
    float4 w0 = *(const float4*)(norm_w + co);
    float4 w1 = *(const float4*)(norm_w + co + 4);
    ushort4 o0, o1;
    o0.x = f2b(b2f(v0.x) * s * w0.x); o0.y = f2b(b2f(v0.y) * s * w0.y);
    o0.z = f2b(b2f(v0.z) * s * w0.z); o0.w = f2b(b2f(v0.w) * s * w0.w);
    o1.x = f2b(b2f(v1.x) * s * w1.x); o1.y = f2b(b2f(v1.y) * s * w1.y);
    o1.z = f2b(b2f(v1.z) * s * w1.z); o1.w = f2b(b2f(v1.w) * s * w1.w);
    *(ushort4*)yp = o0;
    *(ushort4*)(yp + 4) = o1;
  }
}

// ---------------------------------------------------------------------------
extern "C" void kernel_launch(void* const* d_in, const int* in_sizes, int n_in,
                              void* d_out, int out_size, void* d_ws, size_t ws_size,
                              hipStream_t stream)
{
  const float* x         = (const float*)d_in[0];
  const float* in_proj_w = (const float*)d_in[1];
  const float* conv_w    = (const float*)d_in[2];
  const float* conv_b    = (const float*)d_in[3];
  const float* dt_bias   = (const float*)d_in[4];
  const float* A_log     = (const float*)d_in[5];
  const float* D_skip    = (const float*)d_in[6];
  const float* norm_w    = (const float*)d_in[7];
  const float* ssm_out_w = (const float*)d_in[8];
  const float* fuse_w    = (const float*)d_in[9];
  const float* fuse_b    = (const float*)d_in[10];
  float* out = (float*)d_out;

  const size_t ZX_E  = (size_t)M_ROWS * D_PROJC;     // 38,010,880
  const size_t XBC_E = (size_t)M_ROWS * CONV_DIMC;   // 20,971,520
  const size_t ST_E  = 33554432;
  const size_t YC_E  = (size_t)M_ROWS * D_CAT;       // 33,554,432
  const size_t AC_E  = 262144;                       // f32 elems

  // batched (ndir=2) layout needs ~353 MiB; fall back to shared buffers
  // (ndir=1, two sequential passes) if the workspace is smaller.
  size_t need2 = (ZX_E + 2 * XBC_E + 2 * ST_E + YC_E + 2 * 524288 + 1048576) * 2
               + 4 * AC_E * 4;
  const int nd = (ws_size >= need2) ? 2 : 1;

  bfu* zx     = (bfu*)d_ws;
  bfu* xBC    = zx + ZX_E;
  bfu* states = xBC + (size_t)nd * XBC_E;
  bfu* ycat   = states + (size_t)nd * ST_E;
  float* acum = (float*)(ycat + YC_E);
  float* dtg  = acum + (size_t)nd * AC_E;
  bfu* ssmTb  = (bfu*)(dtg + (size_t)nd * AC_E);     // 1024 x 512 bf16
  bfu* fuseA  = ssmTb + 524288;                      // 1024 x 512 bf16
  bfu* wcmb   = fuseA + 524288;                      // 1024 x 1024 bf16
  // transient aliases inside the states region (dead before states_mfma_k):
  bfu* xb = states;                    // 16384 x 512 bf16
  bfu* wb = states + 8388608;          // 2560  x 512 bf16 (padded for 256-tile)

  const size_t xbc_str = (nd == 2) ? XBC_E : 0;
  const size_t st_str  = (nd == 2) ? ST_E  : 0;
  const size_t ac_str  = (nd == 2) ? AC_E  : 0;

  cvt_x_k<<<8192, 256, 0, stream>>>(x, xb);
  cvt_w_k<<<1280, 256, 0, stream>>>(in_proj_w, wb);     // rows 2320..2559 zero
  transpose_k<<<2048, 256, 0, stream>>>(ssm_out_w, ssmTb);
  cvt_fuse_k<<<512, 256, 0, stream>>>(fuse_w, fuseA);

  // wcmb[(o*2+dir)][j] = sum_k fuse_w[o, dir*512+k] * ssm_out_w[k, j]
  mfma_nt<<<dim3(8, 8), 256, 0, stream>>>(
      fuseA, 512, ssmTb, 512, wcmb, 1024, 1024, 512, nullptr, 0);

  // in_proj: zx = x @ in_proj_w^T  (8-phase 256x256 pipeline)
  mfma_nt_8p<<<dim3(10, 64), 512, 0, stream>>>(
      xb, 512, wb, 512, zx, D_PROJC, D_PROJC, 512);

  for (int dl = 0; dl < 2; dl += nd) {
    conv_k<<<dim3(5, 2048 * nd), 256, 0, stream>>>(
        zx, conv_w, conv_b, xBC, xbc_str, dl);
    states_mfma_k<<<512 * nd, 256, 0, stream>>>(
        zx, xBC, xbc_str, dt_bias, A_log, acum, dtg, ac_str, states, st_str, dl);
    scan_k<<<512 * nd, 256, 0, stream>>>(states, st_str, acum, ac_str);
    y_mfma_k<<<256 * nd, 256, 0, stream>>>(
        xBC, xbc_str, states, st_str, acum, dtg, ac_str, D_skip,
        zx, norm_w, ycat, dl);
  }

  // single fused output GEMM: out = ycat @ wcmb^T + fuse_b  (K = 2048)
  mfma_nt<<<dim3(4, 128), 256, 0, stream>>>(
      ycat, D_CAT, wcmb, D_CAT, out, 512, 512, D_CAT, fuse_b, 1);
}

// Round 9
// 517.865 us; speedup vs baseline: 1.1586x; 1.1586x over previous
//
#include <hip/hip_runtime.h>
#include <cstddef>

// Problem constants
#define B_SZ     2
#define L_SEQ    8192
#define D_INNERC 1024
#define D_CAT    2048         // concat of fwd|rev y halves
#define NHEADSC  16
#define CHUNKC   64
#define NCHUNKC  128          // L_SEQ / CHUNK
#define CONV_DIMC 1280
#define D_PROJC  2320
#define M_ROWS   16384        // B_SZ * L_SEQ

typedef unsigned short bfu;   // raw bf16 bits

using bf16x8 = __attribute__((ext_vector_type(8))) short;
using f32x4  = __attribute__((ext_vector_type(4))) float;

__device__ __forceinline__ float silu_(float v) { return v / (1.f + expf(-v)); }

__device__ __forceinline__ float b2f(bfu u) {
  return __uint_as_float((unsigned)u << 16);
}
__device__ __forceinline__ bfu f2b(float f) {
  unsigned x = __float_as_uint(f);
  return (bfu)((x + 0x7fffu + ((x >> 16) & 1u)) >> 16);   // RNE
}

__device__ __forceinline__ float4 ld4(const float* p) { return *(const float4*)p; }
__device__ __forceinline__ float4 ld4(const bfu* p) {
  ushort4 u = *(const ushort4*)p;
  float4 f;
  f.x = b2f(u.x); f.y = b2f(u.y); f.z = b2f(u.z); f.w = b2f(u.w);
  return f;
}
__device__ __forceinline__ void st4(float* p, float4 v) { *(float4*)p = v; }
__device__ __forceinline__ void st4(bfu* p, float4 v) {
  ushort4 u;
  u.x = f2b(v.x); u.y = f2b(v.y); u.z = f2b(v.z); u.w = f2b(v.w);
  *(ushort4*)p = u;
}

__device__ __forceinline__ void gl_lds16(const bfu* g, bfu* l) {
  __builtin_amdgcn_global_load_lds(
      (const __attribute__((address_space(1))) unsigned int*)g,
      (__attribute__((address_space(3))) unsigned int*)l, 16, 0, 0);
}

__device__ __forceinline__ int pos_of(int b, int c, int l, int dir) {
  int t = c * CHUNKC + l;
  return dir ? (b * L_SEQ + (L_SEQ - 1) - t) : (b * L_SEQ + t);
}

// ---------------------------------------------------------------------------
// MFMA GEMM (NT): C[m][n] = sum_k A[m][k] * Bw[n][k].  A,B bf16, K-contig.
// 128x128 tile, BK=64 (K % 64 == 0), 256 thr = 4 waves 2x2, 4x4x(2 k-step)
// MFMAs of 16x16x32.  mode: 0 -> store bf16;  1 -> store f32 (+bias)
// ---------------------------------------------------------------------------
__global__ __launch_bounds__(256)
void mfma_nt(const bfu* __restrict__ A, int lda,
             const bfu* __restrict__ Bw, int ldb,
             void* __restrict__ Cv, int ldc,
             int N, int K, const float* __restrict__ bias, int mode)
{
  __shared__ bfu sh[16384];           // 32 KB: As | Bs, reused by epilogue
  bfu* As = sh;                       // 128 x 64
  bfu* Bs = sh + 8192;                // 128 x 64
  const int tid  = threadIdx.x;
  const int lane = tid & 63;
  const int wave = __builtin_amdgcn_readfirstlane(tid >> 6);
  const int wm = wave & 1, wn = wave >> 1;

  const int num_n = gridDim.x;
  const int flat  = blockIdx.y * num_n + blockIdx.x;
  const int xcd   = flat & 7;
  const int g     = flat >> 3;
  const int n0 = (g % num_n) * 128;
  const int m0 = ((g / num_n) * 8 + xcd) * 128;

  f32x4 acc[4][4];
#pragma unroll
  for (int i = 0; i < 4; ++i)
#pragma unroll
    for (int j = 0; j < 4; ++j)
      acc[i][j] = (f32x4){0.f, 0.f, 0.f, 0.f};

  const int ro   = lane >> 3;          // row within 8-row staging slice
  const int slot = lane & 7;           // stored colgroup slot

  for (int k0 = 0; k0 < K; k0 += 64) {
    __syncthreads();
    // each wave stages rows [wave*32, wave*32+32) of A and B, 8 rows/call
#pragma unroll
    for (int si = 0; si < 4; ++si) {
      int r = wave * 32 + si * 8 + ro;
      int cg = slot ^ (r & 7);
      gl_lds16(A  + (size_t)(m0 + r) * lda + k0 + cg * 8, As + (wave * 32 + si * 8) * 64);
      gl_lds16(Bw + (size_t)(n0 + r) * ldb + k0 + cg * 8, Bs + (wave * 32 + si * 8) * 64);
    }
    __syncthreads();

#pragma unroll
    for (int ks = 0; ks < 2; ++ks) {
      bf16x8 af[4], bfr[4];
#pragma unroll
      for (int i = 0; i < 4; ++i) {
        int ra = wm * 64 + i * 16 + (lane & 15);
        int ca = (ks * 4 + (lane >> 4)) ^ (ra & 7);
        af[i] = *(const bf16x8*)(As + ra * 64 + ca * 8);
        int rb = wn * 64 + i * 16 + (lane & 15);
        int cb = (ks * 4 + (lane >> 4)) ^ (rb & 7);
        bfr[i] = *(const bf16x8*)(Bs + rb * 64 + cb * 8);
      }
#pragma unroll
      for (int i = 0; i < 4; ++i)
#pragma unroll
        for (int j = 0; j < 4; ++j)
          acc[i][j] = __builtin_amdgcn_mfma_f32_16x16x32_bf16(af[i], bfr[j], acc[i][j], 0, 0, 0);
    }
  }

  // ---- epilogue: repack through LDS, coalesced dwordx4 stores ----
  // C/D layout: col = lane&15, row = (lane>>4)*4 + reg
  __syncthreads();
  if (mode == 0) {
    // whole 128x128 bf16 tile fits in 32 KB
#pragma unroll
    for (int i = 0; i < 4; ++i)
#pragma unroll
      for (int j = 0; j < 4; ++j)
#pragma unroll
        for (int r = 0; r < 4; ++r) {
          int ml = wm * 64 + i * 16 + (lane >> 4) * 4 + r;
          int nl = wn * 64 + j * 16 + (lane & 15);
          sh[ml * 128 + nl] = f2b(acc[i][j][r]);
        }
    __syncthreads();
    bfu* Cb = (bfu*)Cv;
#pragma unroll
    for (int rr = 0; rr < 8; ++rr) {
      int idx = rr * 256 + tid;            // 8-elem group id, 0..2047
      int row = idx >> 4, co = (idx & 15) * 8;
      if (n0 + co < N) {                   // N is 8-aligned
        *(ulonglong2*)(Cb + (size_t)(m0 + row) * ldc + n0 + co) =
            *(const ulonglong2*)(sh + row * 128 + co);
      }
    }
  } else {
    float* Cf = (float*)Cv;
    float* shf = (float*)sh;               // 64 rows x 128 f32 per pass
#pragma unroll
    for (int p = 0; p < 2; ++p) {
      if (wm == p) {
#pragma unroll
        for (int i = 0; i < 4; ++i)
#pragma unroll
          for (int j = 0; j < 4; ++j)
#pragma unroll
            for (int r = 0; r < 4; ++r) {
              int ml = i * 16 + (lane >> 4) * 4 + r;   // 0..63
              int nl = wn * 64 + j * 16 + (lane & 15);
              shf[ml * 128 + nl] = acc[i][j][r];
            }
      }
      __syncthreads();
#pragma unroll
      for (int rr = 0; rr < 8; ++rr) {
        int idx = rr * 256 + tid;          // float4 group id, 0..2047
        int row = idx >> 5, co = (idx & 31) * 4;
        int n = n0 + co;
        if (n < N) {
          float4 v = *(float4*)(shf + row * 128 + co);
          float* cp = Cf + (size_t)(m0 + p * 64 + row) * ldc + n;
          if (bias) {
            v.x += bias[n]; v.y += bias[n + 1]; v.z += bias[n + 2]; v.w += bias[n + 3];
          }
          *(float4*)cp = v;
        }
      }
      __syncthreads();
    }
  }
}

// ---------------------------------------------------------------------------
// 8-phase 256x256 MFMA GEMM (NT), bf16 out.  512 thr = 8 waves (2M x 4N),
// BK=64, K % 128 == 0, M % 256 == 0.  LDS 128 KB: double-buffered A,B tiles.
// Counted vmcnt(4) at phases 4 and 8 only (never 0 mid-loop).
// ---------------------------------------------------------------------------
__global__ __launch_bounds__(512)
void mfma_nt_8p(const bfu* __restrict__ A, int lda,
                const bfu* __restrict__ Bw, int ldb,
                bfu* __restrict__ C, int ldc, int N, int K)
{
  __shared__ bfu sh[65536];            // 128 KB; reused by epilogue (256x256)
  bfu* As0 = sh;                        // tile kt   (even), A 256x64
  bfu* As1 = sh + 16384;                // tile kt+1 (odd),  A 256x64
  bfu* Bs0 = sh + 32768;                // tile kt   B 256x64
  bfu* Bs1 = sh + 49152;                // tile kt+1 B 256x64

  const int tid  = threadIdx.x;
  const int lane = tid & 63;
  const int w    = __builtin_amdgcn_readfirstlane(tid >> 6);
  const int wm = w & 1, wn = w >> 1;    // 2 x 4 wave grid
  const int q = lane >> 4, t = lane & 15;

  const int num_n = gridDim.x;
  const int flat  = blockIdx.y * num_n + blockIdx.x;
  const int xcd   = flat & 7;
  const int g     = flat >> 3;
  const int n0 = (g % num_n) * 256;
  const int m0 = ((g / num_n) * 8 + xcd) * 256;

  auto STG = [&](const bfu* __restrict__ X, int ldx, int x0, int kt, int h,
                 bfu* dst) {
#pragma unroll
    for (int ci = 0; ci < 2; ++ci) {
      int rb = h * 128 + ci * 64 + w * 8;          // wave-uniform row base
      int r  = rb + (lane >> 3);
      int cg = (lane & 7) ^ (r & 7);
      gl_lds16(X + (size_t)(x0 + r) * ldx + kt * 64 + cg * 8, dst + rb * 64);
    }
  };
  auto FR = [&](const bfu* tile, int R, int gg) -> bf16x8 {
    return *(const bf16x8*)(tile + R * 64 + ((gg ^ (R & 7)) * 8));
  };

  f32x4 acc[8][4];
#pragma unroll
  for (int i = 0; i < 8; ++i)
#pragma unroll
    for (int j = 0; j < 4; ++j)
      acc[i][j] = (f32x4){0.f, 0.f, 0.f, 0.f};

  // prologue: tile0 (B,A) + tile1 B; tile1 A is staged in iter0 p0/p1
  STG(Bw, ldb, n0, 0, 0, Bs0); STG(Bw, ldb, n0, 0, 1, Bs0);
  STG(A,  lda, m0, 0, 0, As0); STG(A,  lda, m0, 0, 1, As0);
  STG(Bw, ldb, n0, 1, 0, Bs1); STG(Bw, ldb, n0, 1, 1, Bs1);
  asm volatile("s_waitcnt vmcnt(4)" ::: "memory");   // tile0 landed
  __builtin_amdgcn_s_barrier();

  const int nIter = K >> 7;            // K % 128 == 0
  bf16x8 bfr[4][2];
  for (int it = 0; it < nIter; ++it) {
    const int kt = it * 2;
    const bool last = (it == nIter - 1);

    // ---- K-tile kt (As0/Bs0), phases 0..3 ----
#pragma unroll
    for (int p = 0; p < 4; ++p) {
      bf16x8 af[2][2];
#pragma unroll
      for (int ii = 0; ii < 2; ++ii)
#pragma unroll
        for (int ks = 0; ks < 2; ++ks)
          af[ii][ks] = FR(As0, wm * 128 + (2 * p + ii) * 16 + t, ks * 4 + q);
      if (p == 0) {
#pragma unroll
        for (int j = 0; j < 4; ++j)
#pragma unroll
          for (int ks = 0; ks < 2; ++ks)
            bfr[j][ks] = FR(Bs0, wn * 64 + j * 16 + t, ks * 4 + q);
      }
      if (p == 0)          STG(A,  lda, m0, kt + 1, 0, As1);
      if (p == 1)          STG(A,  lda, m0, kt + 1, 1, As1);
      if (p == 2 && !last) STG(Bw, ldb, n0, kt + 2, 0, Bs0);
      if (p == 3 && !last) STG(Bw, ldb, n0, kt + 2, 1, Bs0);
      if (p == 3) {
        if (last) asm volatile("s_waitcnt vmcnt(0)" ::: "memory");
        else      asm volatile("s_waitcnt vmcnt(4)" ::: "memory");
      }
      __builtin_amdgcn_s_barrier();
      __builtin_amdgcn_s_setprio(1);
#pragma unroll
      for (int ks = 0; ks < 2; ++ks)
#pragma unroll
        for (int ii = 0; ii < 2; ++ii)
#pragma unroll
          for (int j = 0; j < 4; ++j)
            acc[2 * p + ii][j] = __builtin_amdgcn_mfma_f32_16x16x32_bf16(
                af[ii][ks], bfr[j][ks], acc[2 * p + ii][j], 0, 0, 0);
      __builtin_amdgcn_s_setprio(0);
      __builtin_amdgcn_s_barrier();
    }

    // ---- K-tile kt+1 (As1/Bs1), phases 4..7 ----
#pragma unroll
    for (int p = 0; p < 4; ++p) {
      bf16x8 af[2][2];
#pragma unroll
      for (int ii = 0; ii < 2; ++ii)
#pragma unroll
        for (int ks = 0; ks < 2; ++ks)
          af[ii][ks] = FR(As1, wm * 128 + (2 * p + ii) * 16 + t, ks * 4 + q);
      if (p == 0) {
#pragma unroll
        for (int j = 0; j < 4; ++j)
#pragma unroll
          for (int ks = 0; ks < 2; ++ks)
            bfr[j][ks] = FR(Bs1, wn * 64 + j * 16 + t, ks * 4 + q);
      }
      if (p == 0 && !last) STG(A,  lda, m0, kt + 2, 0, As0);
      if (p == 1 && !last) STG(A,  lda, m0, kt + 2, 1, As0);
      if (p == 2 && !last) STG(Bw, ldb, n0, kt + 3, 0, Bs1);
      if (p == 3 && !last) STG(Bw, ldb, n0, kt + 3, 1, Bs1);
      if (p == 3 && !last) asm volatile("s_waitcnt vmcnt(4)" ::: "memory");
      __builtin_amdgcn_s_barrier();
      __builtin_amdgcn_s_setprio(1);
#pragma unroll
      for (int ks = 0; ks < 2; ++ks)
#pragma unroll
        for (int ii = 0; ii < 2; ++ii)
#pragma unroll
          for (int j = 0; j < 4; ++j)
            acc[2 * p + ii][j] = __builtin_amdgcn_mfma_f32_16x16x32_bf16(
                af[ii][ks], bfr[j][ks], acc[2 * p + ii][j], 0, 0, 0);
      __builtin_amdgcn_s_setprio(0);
      __builtin_amdgcn_s_barrier();
    }
  }

  // ---- epilogue: repack 256x256 bf16 through LDS (exactly 128 KB) ----
#pragma unroll
  for (int i = 0; i < 8; ++i)
#pragma unroll
    for (int j = 0; j < 4; ++j)
#pragma unroll
      for (int r = 0; r < 4; ++r) {
        int ml = wm * 128 + i * 16 + q * 4 + r;
        int nl = wn * 64 + j * 16 + t;
        sh[ml * 256 + nl] = f2b(acc[i][j][r]);
      }
  __syncthreads();
#pragma unroll
  for (int rr = 0; rr < 16; ++rr) {
    int idx = rr * 512 + tid;            // 8-elem group id, 0..8191
    int row = idx >> 5, co = (idx & 31) * 8;
    if (n0 + co < N) {                   // N is 8-aligned
      *(ulonglong2*)(C + (size_t)(m0 + row) * ldc + n0 + co) =
          *(const ulonglong2*)(sh + row * 256 + co);
    }
  }
}

// ---------------------------------------------------------------------------
// setup converts (all fp32 -> bf16)
// ---------------------------------------------------------------------------
__global__ __launch_bounds__(256)
void cvt_x_k(const float* __restrict__ in, bfu* __restrict__ out)
{
  int q = blockIdx.x * 256 + threadIdx.x;
  st4(out + (size_t)q * 4, ld4(in + (size_t)q * 4));
}

__global__ __launch_bounds__(256)
void cvt_w_k(const float* __restrict__ in, bfu* __restrict__ out)
{
  int q = blockIdx.x * 256 + threadIdx.x;
  int row = q >> 7, c4 = (q & 127) << 2;
  float4 v = {0.f, 0.f, 0.f, 0.f};
  if (row < D_PROJC) v = ld4(in + (size_t)row * 512 + c4);
  st4(out + (size_t)row * 512 + c4, v);
}

// ssm_out_w (512 x 1024 f32) -> ssmTb (1024 x 512 bf16)
__global__ __launch_bounds__(256)
void transpose_k(const float* __restrict__ in, bfu* __restrict__ out)
{
  int idx = blockIdx.x * 256 + threadIdx.x;   // 0 .. 524287
  int j = idx >> 9, k = idx & 511;
  out[idx] = f2b(in[k * 1024 + j]);
}

// fuse_w (512 x 1024 f32) -> fuseA (1024 x 512 bf16), row m' = o*2 + dir
__global__ __launch_bounds__(256)
void cvt_fuse_k(const float* __restrict__ in, bfu* __restrict__ out)
{
  int q = blockIdx.x * 256 + threadIdx.x;     // 0 .. 131071 (4-elem groups)
  int m = q >> 7, kg = (q & 127) << 2;        // m' = o*2 + dir
  int o = m >> 1, dir = m & 1;
  float4 v = ld4(in + (size_t)o * 1024 + dir * 512 + kg);
  st4(out + (size_t)m * 512 + kg, v);
}

// ---------------------------------------------------------------------------
// Depthwise conv + bias + SiLU, 8 outputs per thread (taps staged in regs).
// Dir-batched: grid (5, 2048*ndir); blockIdx.y>>11 selects dir slot.
// ---------------------------------------------------------------------------
__global__ __launch_bounds__(256)
void conv_k(const bfu* __restrict__ zx, const float* __restrict__ conv_w,
            const float* __restrict__ conv_b, bfu* __restrict__ xBC,
            size_t xbc_str, int dir_lo)
{
  int di  = blockIdx.y >> 11;
  int dir = dir_lo + di;
  bfu* xBCd = xBC + (size_t)di * xbc_str;
  int ch = blockIdx.x * 256 + threadIdx.x;   // 0..1279
  int m0 = (blockIdx.y & 2047) * 8;          // global row base
  int b  = m0 >> 13, tb = m0 & (L_SEQ - 1);
  float w0 = conv_w[ch * 4 + 0], w1 = conv_w[ch * 4 + 1];
  float w2 = conv_w[ch * 4 + 2], w3 = conv_w[ch * 4 + 3];
  float cb = conv_b[ch];
  const bfu* src = zx + 1024 + ch;
  const int shift = dir ? 0 : 3;

  float v[11];
#pragma unroll
  for (int i = 0; i < 11; ++i) {
    int tt = tb + i - shift;
    v[i] = (tt >= 0 && tt < L_SEQ)
         ? b2f(src[(size_t)(b * L_SEQ + tt) * D_PROJC]) : 0.f;
  }
#pragma unroll
  for (int j = 0; j < 8; ++j) {
    float acc = cb;
    if (dir == 0) {
      acc += w0 * v[j] + w1 * v[j + 1] + w2 * v[j + 2] + w3 * v[j + 3];
    } else {
      acc += w0 * v[j + 3] + w1 * v[j + 2] + w2 * v[j + 1] + w3 * v[j];
    }
    xBCd[(size_t)(m0 + j) * CONV_DIMC + ch] = f2b(silu_(acc));
  }
}

// ---------------------------------------------------------------------------
// MFMA states: per (b,c) block, 8 heads/block.  Dir-batched: grid 512*ndir.
// T14 async-stage: head i+1's xh global loads issued into registers before
// head i's compute; consumed at next xsT write.
// ---------------------------------------------------------------------------
__global__ __launch_bounds__(256)
void states_mfma_k(const bfu* __restrict__ zx, const bfu* __restrict__ xBC,
                   size_t xbc_str,
                   const float* __restrict__ dt_bias, const float* __restrict__ A_log,
                   float* __restrict__ acum_g, float* __restrict__ dt_g,
                   size_t ac_str,
                   bfu* __restrict__ states, size_t st_str, int dir_lo)
{
  __shared__ bfu BT[128 * 72];     // [n][l]
  __shared__ bfu xsT[64 * 72];     // [p][l]
  __shared__ float scaleS[8 * 64];

  int di  = blockIdx.x >> 9;
  int dir = dir_lo + di;
  const bfu* xBCd = xBC + (size_t)di * xbc_str;
  float* acumd = acum_g + (size_t)di * ac_str;
  float* dtgd  = dt_g   + (size_t)di * ac_str;
  bfu* statesd = states + (size_t)di * st_str;

  int bid = blockIdx.x & 511;
  int hb = bid >> 8;
  int c = bid & 127, b = (bid >> 7) & 1;
  int tid = threadIdx.x, lane = tid & 63;
  int w = tid >> 6, q = lane >> 4, t = lane & 15;

#pragma unroll
  for (int rr = 0; rr < 2; ++rr) {
    int i = w + rr * 4;
    int h = hb * 8 + i;
    int l = lane;
    int pos = pos_of(b, c, l, dir);
    float dtr = b2f(zx[(size_t)pos * D_PROJC + 2304 + h]) + dt_bias[h];
    float dt = (dtr > 20.f) ? dtr : log1pf(expf(dtr));
    float a = -expf(A_log[h]) * dt;
#pragma unroll
    for (int off = 1; off < 64; off <<= 1) {
      float v = __shfl_up(a, off);
      if (l >= off) a += v;
    }
    float alast = __shfl(a, 63);
    int gi = ((b * NCHUNKC + c) * NHEADSC + h) * 64 + l;
    acumd[gi] = a; dtgd[gi] = dt;
    scaleS[i * 64 + l] = dt * expf(alast - a);
  }

#pragma unroll
  for (int r = 0; r < 8; ++r) {
    int qq = tid + r * 256;
    int l = qq & 63, ng = qq >> 6;
    ushort4 v = *(const ushort4*)(xBCd + (size_t)pos_of(b, c, l, dir) * CONV_DIMC + 1024 + ng * 4);
    BT[(ng * 4 + 0) * 72 + l] = v.x; BT[(ng * 4 + 1) * 72 + l] = v.y;
    BT[(ng * 4 + 2) * 72 + l] = v.z; BT[(ng * 4 + 3) * 72 + l] = v.w;
  }

  ushort4 xr[4];
  auto PREFX = [&](int i) {
    int h = hb * 8 + i;
#pragma unroll
    for (int r = 0; r < 4; ++r) {
      int qq = tid + r * 256;
      int l = qq & 63, pg = qq >> 6;
      xr[r] = *(const ushort4*)(xBCd + (size_t)pos_of(b, c, l, dir) * CONV_DIMC + h * 64 + pg * 4);
    }
  };
  PREFX(0);
  __syncthreads();

  for (int i = 0; i < 8; ++i) {
    int h = hb * 8 + i;
#pragma unroll
    for (int r = 0; r < 4; ++r) {
      int qq = tid + r * 256;
      int l = qq & 63, pg = qq >> 6;
      float s = scaleS[i * 64 + l];
      ushort4 v = xr[r];
      xsT[(pg * 4 + 0) * 72 + l] = f2b(b2f(v.x) * s);
      xsT[(pg * 4 + 1) * 72 + l] = f2b(b2f(v.y) * s);
      xsT[(pg * 4 + 2) * 72 + l] = f2b(b2f(v.z) * s);
      xsT[(pg * 4 + 3) * 72 + l] = f2b(b2f(v.w) * s);
    }
    if (i < 7) PREFX(i + 1);
    __syncthreads();

    bf16x8 axs[2];
#pragma unroll
    for (int ks = 0; ks < 2; ++ks)
      axs[ks] = *(const bf16x8*)(xsT + (w * 16 + t) * 72 + ks * 32 + q * 8);

    f32x4 acc[8];
#pragma unroll
    for (int j = 0; j < 8; ++j) acc[j] = (f32x4){0.f, 0.f, 0.f, 0.f};
#pragma unroll
    for (int ks = 0; ks < 2; ++ks)
#pragma unroll
      for (int j = 0; j < 8; ++j) {
        bf16x8 bB = *(const bf16x8*)(BT + (j * 16 + t) * 72 + ks * 32 + q * 8);
        acc[j] = __builtin_amdgcn_mfma_f32_16x16x32_bf16(axs[ks], bB, acc[j], 0, 0, 0);
      }

    size_t base = ((size_t)(b * NCHUNKC + c) * NHEADSC + h) * 8192;
#pragma unroll
    for (int j = 0; j < 8; ++j)
#pragma unroll
      for (int r = 0; r < 4; ++r) {
        int p = w * 16 + q * 4 + r, n = j * 16 + t;
        statesd[base + p * 128 + n] = f2b(acc[j][r]);
      }
    __syncthreads();
  }
}

// ---------------------------------------------------------------------------
// Inter-chunk scan with explicit next-chunk prefetch.  Dir-batched:
// grid 512*ndir; (b,h,eb) from low 9 bits.  (Round-3 verified inner loop.)
// ---------------------------------------------------------------------------
__global__ __launch_bounds__(256)
void scan_k(bfu* __restrict__ states, size_t st_str,
            const float* __restrict__ acum_g, size_t ac_str)
{
  int di  = blockIdx.x >> 9;
  int bid = blockIdx.x & 511;
  bfu* statesd = states + (size_t)di * st_str;
  const float* acumd = acum_g + (size_t)di * ac_str;

  int eb = bid & 15, h = (bid >> 4) & 15, b = bid >> 8;
  int e = eb * 512 + threadIdx.x * 2;
  bfu* p0 = statesd + ((size_t)(b * NCHUNKC) * NHEADSC + h) * 8192 + e;
  const float* ac = acumd + ((b * NCHUNKC) * NHEADSC + h) * 64 + 63;
  const size_t cstride = (size_t)NHEADSC * 8192;
  const int astride = NHEADSC * 64;

  float pre0 = 0.f, pre1 = 0.f;
  uint raw = *(const uint*)p0;
  float dcur = expf(ac[0]);
  for (int c = 0; c < NCHUNKC; ++c) {
    uint raw_next = 0; float dnext = 0.f;
    if (c < NCHUNKC - 1) {
      raw_next = *(const uint*)(p0 + (c + 1) * cstride);
      dnext = expf(ac[(c + 1) * astride]);
    }
    float v0 = b2f((bfu)(raw & 0xffff));
    float v1 = b2f((bfu)(raw >> 16));
    uint packed = (uint)f2b(pre0) | ((uint)f2b(pre1) << 16);
    *(uint*)(p0 + c * cstride) = packed;
    pre0 = v0 + dcur * pre0;
    pre1 = v1 + dcur * pre1;
    raw = raw_next; dcur = dnext;
  }
}

// ---------------------------------------------------------------------------
// MFMA Y: per (b,c) block, 8 heads/block.  Dir-batched: grid 512*ndir.
// Writes into ycat[m][D_CAT] at column offset dir*1024 (single-GEMM fusion).
// (Round-7 verified form.)
// ---------------------------------------------------------------------------
__global__ __launch_bounds__(256)
void y_mfma_k(const bfu* __restrict__ xBC, size_t xbc_str,
              const bfu* __restrict__ states, size_t st_str,
              const float* __restrict__ acum_g, const float* __restrict__ dt_g,
              size_t ac_str,
              const float* __restrict__ D_skip, bfu* __restrict__ ycat, int dir_lo)
{
  __shared__ bfu smem[30976];
  bfu* Cs  = smem;                      // 64 x 136
  bfu* Bsc = smem + 8704;               // 64 x 136 (B tile; sc overlays)
  bfu* Ps  = smem + 17408;              // 64 x 136
  bfu* xhT = smem + 26112;              // 64 x 72
  float* acumH = (float*)(smem + 30720);
  float* dtH   = acumH + 64;

  int di  = blockIdx.x >> 9;
  int dir = dir_lo + di;
  const bfu* xBCd = xBC + (size_t)di * xbc_str;
  const bfu* statesd = states + (size_t)di * st_str;
  const float* acumd = acum_g + (size_t)di * ac_str;
  const float* dtgd  = dt_g   + (size_t)di * ac_str;

  int bid = blockIdx.x & 511;
  int hb = bid >> 8;
  int c = bid & 127, b = (bid >> 7) & 1;
  int tid = threadIdx.x, lane = tid & 63;
  int w = tid >> 6, q = lane >> 4, t = lane & 15;

#pragma unroll
  for (int r = 0; r < 8; ++r) {
    int qq = tid + r * 256;
    int row = qq >> 5, grp = qq & 31;
    const bfu* src = xBCd + (size_t)pos_of(b, c, row, dir) * CONV_DIMC;
    *(ushort4*)(Cs  + row * 136 + grp * 4) = *(const ushort4*)(src + 1152 + grp * 4);
    *(ushort4*)(Bsc + row * 136 + grp * 4) = *(const ushort4*)(src + 1024 + grp * 4);
  }
  __syncthreads();

  bf16x8 af[4];
#pragma unroll
  for (int ks = 0; ks < 4; ++ks)
    af[ks] = *(const bf16x8*)(Cs + (w * 16 + t) * 136 + ks * 32 + q * 8);

  f32x4 sacc[4];
#pragma unroll
  for (int j = 0; j < 4; ++j) sacc[j] = (f32x4){0.f, 0.f, 0.f, 0.f};
#pragma unroll
  for (int ks = 0; ks < 4; ++ks)
#pragma unroll
    for (int j = 0; j < 4; ++j) {
      bf16x8 bf = *(const bf16x8*)(Bsc + (j * 16 + t) * 136 + ks * 32 + q * 8);
      sacc[j] = __builtin_amdgcn_mfma_f32_16x16x32_bf16(af[ks], bf, sacc[j], 0, 0, 0);
    }

  for (int i = 0; i < 8; ++i) {
    int h = hb * 8 + i;
    __syncthreads();
    size_t pbase = ((size_t)(b * NCHUNKC + c) * NHEADSC + h) * 8192;
#pragma unroll
    for (int r = 0; r < 8; ++r) {
      int qq = tid + r * 256;
      int row = qq >> 5, grp = qq & 31;
      *(ushort4*)(Ps + row * 136 + grp * 4) =
          *(const ushort4*)(statesd + pbase + row * 128 + grp * 4);
    }
#pragma unroll
    for (int r = 0; r < 4; ++r) {
      int qq = tid + r * 256;
      int l = qq & 63, pg = qq >> 6;
      ushort4 v = *(const ushort4*)(xBCd + (size_t)pos_of(b, c, l, dir) * CONV_DIMC + h * 64 + pg * 4);
      xhT[(pg * 4 + 0) * 72 + l] = v.x; xhT[(pg * 4 + 1) * 72 + l] = v.y;
      xhT[(pg * 4 + 2) * 72 + l] = v.z; xhT[(pg * 4 + 3) * 72 + l] = v.w;
    }
    if (tid < 64) {
      int gi = ((b * NCHUNKC + c) * NHEADSC + h) * 64 + tid;
      acumH[tid] = acumd[gi]; dtH[tid] = dtgd[gi];
    }
    __syncthreads();

    f32x4 yacc[4];
#pragma unroll
    for (int j = 0; j < 4; ++j) yacc[j] = (f32x4){0.f, 0.f, 0.f, 0.f};
#pragma unroll
    for (int ks = 0; ks < 4; ++ks)
#pragma unroll
      for (int j = 0; j < 4; ++j) {
        bf16x8 bP = *(const bf16x8*)(Ps + (j * 16 + t) * 136 + ks * 32 + q * 8);
        yacc[j] = __builtin_amdgcn_mfma_f32_16x16x32_bf16(af[ks], bP, yacc[j], 0, 0, 0);
      }

    float Dh = D_skip[h];
    bfu* sc = Bsc;
#pragma unroll
    for (int j = 0; j < 4; ++j)
#pragma unroll
      for (int r = 0; r < 4; ++r) {
        int l = w * 16 + q * 4 + r, s = j * 16 + t;
        float v = 0.f;
        if (s <= l) v = sacc[j][r] * expf(acumH[l] - acumH[s]) * dtH[s];
        if (s == l) v += Dh;
        sc[l * 72 + s] = f2b(v);
      }

    f32x4 acc2[4];
    float dec[4];
#pragma unroll
    for (int r = 0; r < 4; ++r) dec[r] = expf(acumH[w * 16 + q * 4 + r]);
#pragma unroll
    for (int j = 0; j < 4; ++j)
#pragma unroll
      for (int r = 0; r < 4; ++r) acc2[j][r] = yacc[j][r] * dec[r];

#pragma unroll
    for (int ks = 0; ks < 2; ++ks) {
      bf16x8 asc = *(const bf16x8*)(sc + (w * 16 + t) * 72 + ks * 32 + q * 8);
#pragma unroll
      for (int j = 0; j < 4; ++j) {
        bf16x8 bx = *(const bf16x8*)(xhT + (j * 16 + t) * 72 + ks * 32 + q * 8);
        acc2[j] = __builtin_amdgcn_mfma_f32_16x16x32_bf16(asc, bx, acc2[j], 0, 0, 0);
      }
    }

#pragma unroll
    for (int j = 0; j < 4; ++j)
#pragma unroll
      for (int r = 0; r < 4; ++r) {
        int l = w * 16 + q * 4 + r, p = j * 16 + t;
        ycat[(size_t)pos_of(b, c, l, dir) * D_CAT + dir * 1024 + h * 64 + p] =
            f2b(acc2[j][r]);
      }
  }
}

// ---------------------------------------------------------------------------
// Gating (y *= silu(z)) + RMSNorm over 1024 + norm_w, in place on the dir
// half of ycat (bf16).  Dir-batched: grid 16384*ndir.
// ---------------------------------------------------------------------------
__global__ __launch_bounds__(256)
void norm_k(bfu* __restrict__ ycat, const bfu* __restrict__ zx,
            const float* __restrict__ norm_w, int dir_lo)
{
  int di  = blockIdx.x >> 14;
  int dir = dir_lo + di;
  int m = blockIdx.x & 16383, tid = threadIdx.x;
  bfu* yp = ycat + (size_t)m * D_CAT + dir * 1024 + tid * 4;
  float4 y = ld4(yp);
  float4 z = ld4(zx + (size_t)m * D_PROJC + tid * 4);
  float4 g;
  g.x = y.x * silu_(z.x); g.y = y.y * silu_(z.y);
  g.z = y.z * silu_(z.z); g.w = y.w * silu_(z.w);
  float ss = g.x * g.x + g.y * g.y + g.z * g.z + g.w * g.w;
#pragma unroll
  for (int off = 32; off >= 1; off >>= 1) ss += __shfl_xor(ss, off);
  __shared__ float red[4];
  int wid = tid >> 6;
  if ((tid & 63) == 0) red[wid] = ss;
  __syncthreads();
  float tot = red[0] + red[1] + red[2] + red[3];
  float scale = rsqrtf(tot * (1.f / 1024.f) + 1e-5f);
  float4 w = *(const float4*)(norm_w + tid * 4);
  g.x *= scale * w.x; g.y *= scale * w.y; g.z *= scale * w.z; g.w *= scale * w.w;
  st4(yp, g);
}

// ---------------------------------------------------------------------------
extern "C" void kernel_launch(void* const* d_in, const int* in_sizes, int n_in,
                              void* d_out, int out_size, void* d_ws, size_t ws_size,
                              hipStream_t stream)
{
  const float* x         = (const float*)d_in[0];
  const float* in_proj_w = (const float*)d_in[1];
  const float* conv_w    = (const float*)d_in[2];
  const float* conv_b    = (const float*)d_in[3];
  const float* dt_bias   = (const float*)d_in[4];
  const float* A_log     = (const float*)d_in[5];
  const float* D_skip    = (const float*)d_in[6];
  const float* norm_w    = (const float*)d_in[7];
  const float* ssm_out_w = (const float*)d_in[8];
  const float* fuse_w    = (const float*)d_in[9];
  const float* fuse_b    = (const float*)d_in[10];
  float* out = (float*)d_out;

  const size_t ZX_E  = (size_t)M_ROWS * D_PROJC;     // 38,010,880
  const size_t XBC_E = (size_t)M_ROWS * CONV_DIMC;   // 20,971,520
  const size_t ST_E  = 33554432;
  const size_t YC_E  = (size_t)M_ROWS * D_CAT;       // 33,554,432
  const size_t AC_E  = 262144;                       // f32 elems

  // batched (ndir=2) layout needs ~353 MiB; fall back to shared buffers
  // (ndir=1, two sequential passes) if the workspace is smaller.
  size_t need2 = (ZX_E + 2 * XBC_E + 2 * ST_E + YC_E + 2 * 524288 + 1048576) * 2
               + 4 * AC_E * 4;
  const int nd = (ws_size >= need2) ? 2 : 1;

  bfu* zx     = (bfu*)d_ws;
  bfu* xBC    = zx + ZX_E;
  bfu* states = xBC + (size_t)nd * XBC_E;
  bfu* ycat   = states + (size_t)nd * ST_E;
  float* acum = (float*)(ycat + YC_E);
  float* dtg  = acum + (size_t)nd * AC_E;
  bfu* ssmTb  = (bfu*)(dtg + (size_t)nd * AC_E);     // 1024 x 512 bf16
  bfu* fuseA  = ssmTb + 524288;                      // 1024 x 512 bf16
  bfu* wcmb   = fuseA + 524288;                      // 1024 x 1024 bf16
  // transient aliases inside the states region (dead before states_mfma_k):
  bfu* xb = states;                    // 16384 x 512 bf16
  bfu* wb = states + 8388608;          // 2560  x 512 bf16 (padded for 256-tile)

  const size_t xbc_str = (nd == 2) ? XBC_E : 0;
  const size_t st_str  = (nd == 2) ? ST_E  : 0;
  const size_t ac_str  = (nd == 2) ? AC_E  : 0;

  cvt_x_k<<<8192, 256, 0, stream>>>(x, xb);
  cvt_w_k<<<1280, 256, 0, stream>>>(in_proj_w, wb);     // rows 2320..2559 zero
  transpose_k<<<2048, 256, 0, stream>>>(ssm_out_w, ssmTb);
  cvt_fuse_k<<<512, 256, 0, stream>>>(fuse_w, fuseA);

  // wcmb[(o*2+dir)][j] = sum_k fuse_w[o, dir*512+k] * ssm_out_w[k, j]
  mfma_nt<<<dim3(8, 8), 256, 0, stream>>>(
      fuseA, 512, ssmTb, 512, wcmb, 1024, 1024, 512, nullptr, 0);

  // in_proj: zx = x @ in_proj_w^T  (8-phase 256x256 pipeline)
  mfma_nt_8p<<<dim3(10, 64), 512, 0, stream>>>(
      xb, 512, wb, 512, zx, D_PROJC, D_PROJC, 512);

  for (int dl = 0; dl < 2; dl += nd) {
    conv_k<<<dim3(5, 2048 * nd), 256, 0, stream>>>(
        zx, conv_w, conv_b, xBC, xbc_str, dl);
    states_mfma_k<<<512 * nd, 256, 0, stream>>>(
        zx, xBC, xbc_str, dt_bias, A_log, acum, dtg, ac_str, states, st_str, dl);
    scan_k<<<512 * nd, 256, 0, stream>>>(states, st_str, acum, ac_str);
    y_mfma_k<<<512 * nd, 256, 0, stream>>>(
        xBC, xbc_str, states, st_str, acum, dtg, ac_str, D_skip, ycat, dl);
    norm_k<<<16384 * nd, 256, 0, stream>>>(ycat, zx, norm_w, dl);
  }

  // single fused output GEMM: out = ycat @ wcmb^T + fuse_b  (K = 2048)
  mfma_nt<<<dim3(4, 128), 256, 0, stream>>>(
      ycat, D_CAT, wcmb, D_CAT, out, 512, 512, D_CAT, fuse_b, 1);
}

// Round 10
// 507.197 us; speedup vs baseline: 1.1829x; 1.0210x over previous
//
#include <hip/hip_runtime.h>
#include <cstddef>

// Problem constants
#define B_SZ     2
#define L_SEQ    8192
#define D_INNERC 1024
#define D_CAT    2048         // concat of fwd|rev y halves
#define NHEADSC  16
#define CHUNKC   64
#define NCHUNKC  128          // L_SEQ / CHUNK
#define CONV_DIMC 1280
#define D_PROJC  2320
#define M_ROWS   16384        // B_SZ * L_SEQ

typedef unsigned short bfu;   // raw bf16 bits

using bf16x8 = __attribute__((ext_vector_type(8))) short;
using f32x4  = __attribute__((ext_vector_type(4))) float;

__device__ __forceinline__ float silu_(float v) { return v / (1.f + expf(-v)); }

__device__ __forceinline__ float b2f(bfu u) {
  return __uint_as_float((unsigned)u << 16);
}
__device__ __forceinline__ bfu f2b(float f) {
  unsigned x = __float_as_uint(f);
  return (bfu)((x + 0x7fffu + ((x >> 16) & 1u)) >> 16);   // RNE
}

__device__ __forceinline__ float4 ld4(const float* p) { return *(const float4*)p; }
__device__ __forceinline__ float4 ld4(const bfu* p) {
  ushort4 u = *(const ushort4*)p;
  float4 f;
  f.x = b2f(u.x); f.y = b2f(u.y); f.z = b2f(u.z); f.w = b2f(u.w);
  return f;
}
__device__ __forceinline__ void st4(float* p, float4 v) { *(float4*)p = v; }
__device__ __forceinline__ void st4(bfu* p, float4 v) {
  ushort4 u;
  u.x = f2b(v.x); u.y = f2b(v.y); u.z = f2b(v.z); u.w = f2b(v.w);
  *(ushort4*)p = u;
}

__device__ __forceinline__ void gl_lds16(const bfu* g, bfu* l) {
  __builtin_amdgcn_global_load_lds(
      (const __attribute__((address_space(1))) unsigned int*)g,
      (__attribute__((address_space(3))) unsigned int*)l, 16, 0, 0);
}

__device__ __forceinline__ int pos_of(int b, int c, int l, int dir) {
  int t = c * CHUNKC + l;
  return dir ? (b * L_SEQ + (L_SEQ - 1) - t) : (b * L_SEQ + t);
}

// ---------------------------------------------------------------------------
// MFMA GEMM (NT): C[m][n] = sum_k A[m][k] * Bw[n][k].  A,B bf16, K-contig.
// 128x128 tile, BK=64 (K % 64 == 0), 256 thr = 4 waves 2x2, 4x4x(2 k-step)
// MFMAs of 16x16x32.  mode: 0 -> store bf16;  1 -> store f32 (+bias)
// ---------------------------------------------------------------------------
__global__ __launch_bounds__(256)
void mfma_nt(const bfu* __restrict__ A, int lda,
             const bfu* __restrict__ Bw, int ldb,
             void* __restrict__ Cv, int ldc,
             int N, int K, const float* __restrict__ bias, int mode)
{
  __shared__ bfu sh[16384];           // 32 KB: As | Bs, reused by epilogue
  bfu* As = sh;                       // 128 x 64
  bfu* Bs = sh + 8192;                // 128 x 64
  const int tid  = threadIdx.x;
  const int lane = tid & 63;
  const int wave = __builtin_amdgcn_readfirstlane(tid >> 6);
  const int wm = wave & 1, wn = wave >> 1;

  const int num_n = gridDim.x;
  const int flat  = blockIdx.y * num_n + blockIdx.x;
  const int xcd   = flat & 7;
  const int g     = flat >> 3;
  const int n0 = (g % num_n) * 128;
  const int m0 = ((g / num_n) * 8 + xcd) * 128;

  f32x4 acc[4][4];
#pragma unroll
  for (int i = 0; i < 4; ++i)
#pragma unroll
    for (int j = 0; j < 4; ++j)
      acc[i][j] = (f32x4){0.f, 0.f, 0.f, 0.f};

  const int ro   = lane >> 3;          // row within 8-row staging slice
  const int slot = lane & 7;           // stored colgroup slot

  for (int k0 = 0; k0 < K; k0 += 64) {
    __syncthreads();
    // each wave stages rows [wave*32, wave*32+32) of A and B, 8 rows/call
#pragma unroll
    for (int si = 0; si < 4; ++si) {
      int r = wave * 32 + si * 8 + ro;
      int cg = slot ^ (r & 7);
      gl_lds16(A  + (size_t)(m0 + r) * lda + k0 + cg * 8, As + (wave * 32 + si * 8) * 64);
      gl_lds16(Bw + (size_t)(n0 + r) * ldb + k0 + cg * 8, Bs + (wave * 32 + si * 8) * 64);
    }
    __syncthreads();

#pragma unroll
    for (int ks = 0; ks < 2; ++ks) {
      bf16x8 af[4], bfr[4];
#pragma unroll
      for (int i = 0; i < 4; ++i) {
        int ra = wm * 64 + i * 16 + (lane & 15);
        int ca = (ks * 4 + (lane >> 4)) ^ (ra & 7);
        af[i] = *(const bf16x8*)(As + ra * 64 + ca * 8);
        int rb = wn * 64 + i * 16 + (lane & 15);
        int cb = (ks * 4 + (lane >> 4)) ^ (rb & 7);
        bfr[i] = *(const bf16x8*)(Bs + rb * 64 + cb * 8);
      }
#pragma unroll
      for (int i = 0; i < 4; ++i)
#pragma unroll
        for (int j = 0; j < 4; ++j)
          acc[i][j] = __builtin_amdgcn_mfma_f32_16x16x32_bf16(af[i], bfr[j], acc[i][j], 0, 0, 0);
    }
  }

  // ---- epilogue: repack through LDS, coalesced dwordx4 stores ----
  // C/D layout: col = lane&15, row = (lane>>4)*4 + reg
  __syncthreads();
  if (mode == 0) {
    // whole 128x128 bf16 tile fits in 32 KB
#pragma unroll
    for (int i = 0; i < 4; ++i)
#pragma unroll
      for (int j = 0; j < 4; ++j)
#pragma unroll
        for (int r = 0; r < 4; ++r) {
          int ml = wm * 64 + i * 16 + (lane >> 4) * 4 + r;
          int nl = wn * 64 + j * 16 + (lane & 15);
          sh[ml * 128 + nl] = f2b(acc[i][j][r]);
        }
    __syncthreads();
    bfu* Cb = (bfu*)Cv;
#pragma unroll
    for (int rr = 0; rr < 8; ++rr) {
      int idx = rr * 256 + tid;            // 8-elem group id, 0..2047
      int row = idx >> 4, co = (idx & 15) * 8;
      if (n0 + co < N) {                   // N is 8-aligned
        *(ulonglong2*)(Cb + (size_t)(m0 + row) * ldc + n0 + co) =
            *(const ulonglong2*)(sh + row * 128 + co);
      }
    }
  } else {
    float* Cf = (float*)Cv;
    float* shf = (float*)sh;               // 64 rows x 128 f32 per pass
#pragma unroll
    for (int p = 0; p < 2; ++p) {
      if (wm == p) {
#pragma unroll
        for (int i = 0; i < 4; ++i)
#pragma unroll
          for (int j = 0; j < 4; ++j)
#pragma unroll
            for (int r = 0; r < 4; ++r) {
              int ml = i * 16 + (lane >> 4) * 4 + r;   // 0..63
              int nl = wn * 64 + j * 16 + (lane & 15);
              shf[ml * 128 + nl] = acc[i][j][r];
            }
      }
      __syncthreads();
#pragma unroll
      for (int rr = 0; rr < 8; ++rr) {
        int idx = rr * 256 + tid;          // float4 group id, 0..2047
        int row = idx >> 5, co = (idx & 31) * 4;
        int n = n0 + co;
        if (n < N) {
          float4 v = *(float4*)(shf + row * 128 + co);
          float* cp = Cf + (size_t)(m0 + p * 64 + row) * ldc + n;
          if (bias) {
            v.x += bias[n]; v.y += bias[n + 1]; v.z += bias[n + 2]; v.w += bias[n + 3];
          }
          *(float4*)cp = v;
        }
      }
      __syncthreads();
    }
  }
}

// ---------------------------------------------------------------------------
// 8-phase 256x128 MFMA GEMM (NT), bf16 out.  512 thr = 8 waves (4M x 2N),
// BK=64, K % 128 == 0, M % 256 == 0, N-tiles of 128.  LDS 96 KB: dbuf A
// (2 x 32 KB) + dbuf B (2 x 16 KB).  Grid (N/128, M/256) -> exact CU-round
// quantization (1280 blocks = 5 x 256).  Counted vmcnt(2) at phases 4/8
// (invariant: next B-tile in flight across iterations); vmcnt(0) only at
// the last iteration's phase 4.
// ---------------------------------------------------------------------------
__global__ __launch_bounds__(512)
void mfma_nt_8p(const bfu* __restrict__ A, int lda,
                const bfu* __restrict__ Bw, int ldb,
                bfu* __restrict__ C, int ldc, int N, int K)
{
  __shared__ bfu sh[49152];            // 96 KB; epilogue reuses (256x128=64KB)
  bfu* As0 = sh;                        // A tile kt   (even), 256x64
  bfu* As1 = sh + 16384;                // A tile kt+1 (odd),  256x64
  bfu* Bs0 = sh + 32768;                // B tile kt   128x64
  bfu* Bs1 = sh + 40960;                // B tile kt+1 128x64

  const int tid  = threadIdx.x;
  const int lane = tid & 63;
  const int w    = __builtin_amdgcn_readfirstlane(tid >> 6);
  const int wm = w & 3, wn = w >> 2;    // 4 x 2 wave grid
  const int q = lane >> 4, t = lane & 15;

  const int num_n = gridDim.x;
  const int flat  = blockIdx.y * num_n + blockIdx.x;
  const int xcd   = flat & 7;
  const int g     = flat >> 3;
  const int n0 = (g % num_n) * 128;
  const int m0 = ((g / num_n) * 8 + xcd) * 256;

  // stage 128 rows x 64 cols (16 KB): 2 gl_lds per thread.
  auto STG = [&](const bfu* __restrict__ X, int ldx, int x0, int kt, int h,
                 bfu* dst) {
#pragma unroll
    for (int ci = 0; ci < 2; ++ci) {
      int rb = h * 128 + ci * 64 + w * 8;          // wave-uniform row base
      int r  = rb + (lane >> 3);
      int cg = (lane & 7) ^ (r & 7);
      gl_lds16(X + (size_t)(x0 + r) * ldx + kt * 64 + cg * 8, dst + rb * 64);
    }
  };
  auto FR = [&](const bfu* tile, int R, int gg) -> bf16x8 {
    return *(const bf16x8*)(tile + R * 64 + ((gg ^ (R & 7)) * 8));
  };

  f32x4 acc[4][4];
#pragma unroll
  for (int i = 0; i < 4; ++i)
#pragma unroll
    for (int j = 0; j < 4; ++j)
      acc[i][j] = (f32x4){0.f, 0.f, 0.f, 0.f};

  // prologue: B(0), A(0) both halves, B(1).  Need tile0 landed; keep B(1)
  // (2 newest loads) in flight -> vmcnt(2).
  STG(Bw, ldb, n0, 0, 0, Bs0);
  STG(A,  lda, m0, 0, 0, As0); STG(A,  lda, m0, 0, 1, As0);
  STG(Bw, ldb, n0, 1, 0, Bs1);
  asm volatile("s_waitcnt vmcnt(2)" ::: "memory");
  __builtin_amdgcn_s_barrier();

  const int nIter = K >> 7;            // K % 128 == 0
  bf16x8 bfr[4][2];
  for (int it = 0; it < nIter; ++it) {
    const int kt = it * 2;
    const bool last = (it == nIter - 1);

    // ---- K-tile kt (As0/Bs0), phases 0..3 ----
    // entering in-flight: B(kt+1) [2 loads]
#pragma unroll
    for (int p = 0; p < 4; ++p) {
      bf16x8 af[2];
#pragma unroll
      for (int ks = 0; ks < 2; ++ks)
        af[ks] = FR(As0, wm * 64 + p * 16 + t, ks * 4 + q);
      if (p == 0) {
#pragma unroll
        for (int j = 0; j < 4; ++j)
#pragma unroll
          for (int ks = 0; ks < 2; ++ks)
            bfr[j][ks] = FR(Bs0, wn * 64 + j * 16 + t, ks * 4 + q);
      }
      if (p == 0)          STG(A,  lda, m0, kt + 1, 0, As1);
      if (p == 1)          STG(A,  lda, m0, kt + 1, 1, As1);
      if (p == 2 && !last) STG(Bw, ldb, n0, kt + 2, 0, Bs0);
      if (p == 3) {
        // outstanding: [B(kt+1)] + A(kt+1) (+ B(kt+2) if !last)
        if (last) asm volatile("s_waitcnt vmcnt(0)" ::: "memory");
        else      asm volatile("s_waitcnt vmcnt(2)" ::: "memory");
      }
      __builtin_amdgcn_s_barrier();
      __builtin_amdgcn_s_setprio(1);
#pragma unroll
      for (int ks = 0; ks < 2; ++ks)
#pragma unroll
        for (int j = 0; j < 4; ++j)
          acc[p][j] = __builtin_amdgcn_mfma_f32_16x16x32_bf16(
              af[ks], bfr[j][ks], acc[p][j], 0, 0, 0);
      __builtin_amdgcn_s_setprio(0);
      __builtin_amdgcn_s_barrier();
    }

    // ---- K-tile kt+1 (As1/Bs1), phases 4..7 ----
    // entering in-flight: B(kt+2) [2 loads] (none if last)
#pragma unroll
    for (int p = 0; p < 4; ++p) {
      bf16x8 af[2];
#pragma unroll
      for (int ks = 0; ks < 2; ++ks)
        af[ks] = FR(As1, wm * 64 + p * 16 + t, ks * 4 + q);
      if (p == 0) {
#pragma unroll
        for (int j = 0; j < 4; ++j)
#pragma unroll
          for (int ks = 0; ks < 2; ++ks)
            bfr[j][ks] = FR(Bs1, wn * 64 + j * 16 + t, ks * 4 + q);
      }
      if (p == 0 && !last) STG(A,  lda, m0, kt + 2, 0, As0);
      if (p == 1 && !last) STG(A,  lda, m0, kt + 2, 1, As0);
      if (p == 2 && !last) STG(Bw, ldb, n0, kt + 3, 0, Bs1);
      if (p == 3 && !last) asm volatile("s_waitcnt vmcnt(2)" ::: "memory");
      __builtin_amdgcn_s_barrier();
      __builtin_amdgcn_s_setprio(1);
#pragma unroll
      for (int ks = 0; ks < 2; ++ks)
#pragma unroll
        for (int j = 0; j < 4; ++j)
          acc[p][j] = __builtin_amdgcn_mfma_f32_16x16x32_bf16(
              af[ks], bfr[j][ks], acc[p][j], 0, 0, 0);
      __builtin_amdgcn_s_setprio(0);
      __builtin_amdgcn_s_barrier();
    }
  }

  // ---- epilogue: repack 256x128 bf16 through LDS (64 KB of the 96) ----
#pragma unroll
  for (int i = 0; i < 4; ++i)
#pragma unroll
    for (int j = 0; j < 4; ++j)
#pragma unroll
      for (int r = 0; r < 4; ++r) {
        int ml = wm * 64 + i * 16 + q * 4 + r;
        int nl = wn * 64 + j * 16 + t;
        sh[ml * 128 + nl] = f2b(acc[i][j][r]);
      }
  __syncthreads();
#pragma unroll
  for (int rr = 0; rr < 8; ++rr) {
    int idx = rr * 512 + tid;            // 8-elem group id, 0..4095
    int row = idx >> 4, co = (idx & 15) * 8;
    if (n0 + co < N) {                   // N is 8-aligned
      *(ulonglong2*)(C + (size_t)(m0 + row) * ldc + n0 + co) =
          *(const ulonglong2*)(sh + row * 128 + co);
    }
  }
}

// ---------------------------------------------------------------------------
// setup converts (all fp32 -> bf16)
// ---------------------------------------------------------------------------
__global__ __launch_bounds__(256)
void cvt_x_k(const float* __restrict__ in, bfu* __restrict__ out)
{
  int q = blockIdx.x * 256 + threadIdx.x;
  st4(out + (size_t)q * 4, ld4(in + (size_t)q * 4));
}

__global__ __launch_bounds__(256)
void cvt_w_k(const float* __restrict__ in, bfu* __restrict__ out)
{
  int q = blockIdx.x * 256 + threadIdx.x;
  int row = q >> 7, c4 = (q & 127) << 2;
  float4 v = {0.f, 0.f, 0.f, 0.f};
  if (row < D_PROJC) v = ld4(in + (size_t)row * 512 + c4);
  st4(out + (size_t)row * 512 + c4, v);
}

// ssm_out_w (512 x 1024 f32) -> ssmTb (1024 x 512 bf16)
__global__ __launch_bounds__(256)
void transpose_k(const float* __restrict__ in, bfu* __restrict__ out)
{
  int idx = blockIdx.x * 256 + threadIdx.x;   // 0 .. 524287
  int j = idx >> 9, k = idx & 511;
  out[idx] = f2b(in[k * 1024 + j]);
}

// fuse_w (512 x 1024 f32) -> fuseA (1024 x 512 bf16), row m' = o*2 + dir
__global__ __launch_bounds__(256)
void cvt_fuse_k(const float* __restrict__ in, bfu* __restrict__ out)
{
  int q = blockIdx.x * 256 + threadIdx.x;     // 0 .. 131071 (4-elem groups)
  int m = q >> 7, kg = (q & 127) << 2;        // m' = o*2 + dir
  int o = m >> 1, dir = m & 1;
  float4 v = ld4(in + (size_t)o * 1024 + dir * 512 + kg);
  st4(out + (size_t)m * 512 + kg, v);
}

// ---------------------------------------------------------------------------
// Depthwise conv + bias + SiLU, 8 outputs per thread (taps staged in regs).
// Dir-batched: grid (5, 2048*ndir); blockIdx.y>>11 selects dir slot.
// ---------------------------------------------------------------------------
__global__ __launch_bounds__(256)
void conv_k(const bfu* __restrict__ zx, const float* __restrict__ conv_w,
            const float* __restrict__ conv_b, bfu* __restrict__ xBC,
            size_t xbc_str, int dir_lo)
{
  int di  = blockIdx.y >> 11;
  int dir = dir_lo + di;
  bfu* xBCd = xBC + (size_t)di * xbc_str;
  int ch = blockIdx.x * 256 + threadIdx.x;   // 0..1279
  int m0 = (blockIdx.y & 2047) * 8;          // global row base
  int b  = m0 >> 13, tb = m0 & (L_SEQ - 1);
  float w0 = conv_w[ch * 4 + 0], w1 = conv_w[ch * 4 + 1];
  float w2 = conv_w[ch * 4 + 2], w3 = conv_w[ch * 4 + 3];
  float cb = conv_b[ch];
  const bfu* src = zx + 1024 + ch;
  const int shift = dir ? 0 : 3;

  float v[11];
#pragma unroll
  for (int i = 0; i < 11; ++i) {
    int tt = tb + i - shift;
    v[i] = (tt >= 0 && tt < L_SEQ)
         ? b2f(src[(size_t)(b * L_SEQ + tt) * D_PROJC]) : 0.f;
  }
#pragma unroll
  for (int j = 0; j < 8; ++j) {
    float acc = cb;
    if (dir == 0) {
      acc += w0 * v[j] + w1 * v[j + 1] + w2 * v[j + 2] + w3 * v[j + 3];
    } else {
      acc += w0 * v[j + 3] + w1 * v[j + 2] + w2 * v[j + 1] + w3 * v[j];
    }
    xBCd[(size_t)(m0 + j) * CONV_DIMC + ch] = f2b(silu_(acc));
  }
}

// ---------------------------------------------------------------------------
// MFMA states: per (b,c) block, 8 heads/block.  Dir-batched: grid 512*ndir.
// T14 async-stage: head i+1's xh global loads issued into registers before
// head i's compute; consumed at next xsT write.
// ---------------------------------------------------------------------------
__global__ __launch_bounds__(256)
void states_mfma_k(const bfu* __restrict__ zx, const bfu* __restrict__ xBC,
                   size_t xbc_str,
                   const float* __restrict__ dt_bias, const float* __restrict__ A_log,
                   float* __restrict__ acum_g, float* __restrict__ dt_g,
                   size_t ac_str,
                   bfu* __restrict__ states, size_t st_str, int dir_lo)
{
  __shared__ bfu BT[128 * 72];     // [n][l]
  __shared__ bfu xsT[64 * 72];     // [p][l]
  __shared__ float scaleS[8 * 64];

  int di  = blockIdx.x >> 9;
  int dir = dir_lo + di;
  const bfu* xBCd = xBC + (size_t)di * xbc_str;
  float* acumd = acum_g + (size_t)di * ac_str;
  float* dtgd  = dt_g   + (size_t)di * ac_str;
  bfu* statesd = states + (size_t)di * st_str;

  int bid = blockIdx.x & 511;
  int hb = bid >> 8;
  int c = bid & 127, b = (bid >> 7) & 1;
  int tid = threadIdx.x, lane = tid & 63;
  int w = tid >> 6, q = lane >> 4, t = lane & 15;

#pragma unroll
  for (int rr = 0; rr < 2; ++rr) {
    int i = w + rr * 4;
    int h = hb * 8 + i;
    int l = lane;
    int pos = pos_of(b, c, l, dir);
    float dtr = b2f(zx[(size_t)pos * D_PROJC + 2304 + h]) + dt_bias[h];
    float dt = (dtr > 20.f) ? dtr : log1pf(expf(dtr));
    float a = -expf(A_log[h]) * dt;
#pragma unroll
    for (int off = 1; off < 64; off <<= 1) {
      float v = __shfl_up(a, off);
      if (l >= off) a += v;
    }
    float alast = __shfl(a, 63);
    int gi = ((b * NCHUNKC + c) * NHEADSC + h) * 64 + l;
    acumd[gi] = a; dtgd[gi] = dt;
    scaleS[i * 64 + l] = dt * expf(alast - a);
  }

#pragma unroll
  for (int r = 0; r < 8; ++r) {
    int qq = tid + r * 256;
    int l = qq & 63, ng = qq >> 6;
    ushort4 v = *(const ushort4*)(xBCd + (size_t)pos_of(b, c, l, dir) * CONV_DIMC + 1024 + ng * 4);
    BT[(ng * 4 + 0) * 72 + l] = v.x; BT[(ng * 4 + 1) * 72 + l] = v.y;
    BT[(ng * 4 + 2) * 72 + l] = v.z; BT[(ng * 4 + 3) * 72 + l] = v.w;
  }

  ushort4 xr[4];
  auto PREFX = [&](int i) {
    int h = hb * 8 + i;
#pragma unroll
    for (int r = 0; r < 4; ++r) {
      int qq = tid + r * 256;
      int l = qq & 63, pg = qq >> 6;
      xr[r] = *(const ushort4*)(xBCd + (size_t)pos_of(b, c, l, dir) * CONV_DIMC + h * 64 + pg * 4);
    }
  };
  PREFX(0);
  __syncthreads();

  for (int i = 0; i < 8; ++i) {
    int h = hb * 8 + i;
#pragma unroll
    for (int r = 0; r < 4; ++r) {
      int qq = tid + r * 256;
      int l = qq & 63, pg = qq >> 6;
      float s = scaleS[i * 64 + l];
      ushort4 v = xr[r];
      xsT[(pg * 4 + 0) * 72 + l] = f2b(b2f(v.x) * s);
      xsT[(pg * 4 + 1) * 72 + l] = f2b(b2f(v.y) * s);
      xsT[(pg * 4 + 2) * 72 + l] = f2b(b2f(v.z) * s);
      xsT[(pg * 4 + 3) * 72 + l] = f2b(b2f(v.w) * s);
    }
    if (i < 7) PREFX(i + 1);
    __syncthreads();

    bf16x8 axs[2];
#pragma unroll
    for (int ks = 0; ks < 2; ++ks)
      axs[ks] = *(const bf16x8*)(xsT + (w * 16 + t) * 72 + ks * 32 + q * 8);

    f32x4 acc[8];
#pragma unroll
    for (int j = 0; j < 8; ++j) acc[j] = (f32x4){0.f, 0.f, 0.f, 0.f};
#pragma unroll
    for (int ks = 0; ks < 2; ++ks)
#pragma unroll
      for (int j = 0; j < 8; ++j) {
        bf16x8 bB = *(const bf16x8*)(BT + (j * 16 + t) * 72 + ks * 32 + q * 8);
        acc[j] = __builtin_amdgcn_mfma_f32_16x16x32_bf16(axs[ks], bB, acc[j], 0, 0, 0);
      }

    size_t base = ((size_t)(b * NCHUNKC + c) * NHEADSC + h) * 8192;
#pragma unroll
    for (int j = 0; j < 8; ++j)
#pragma unroll
      for (int r = 0; r < 4; ++r) {
        int p = w * 16 + q * 4 + r, n = j * 16 + t;
        statesd[base + p * 128 + n] = f2b(acc[j][r]);
      }
    __syncthreads();
  }
}

// ---------------------------------------------------------------------------
// Inter-chunk scan with explicit next-chunk prefetch.  Dir-batched:
// grid 512*ndir; (b,h,eb) from low 9 bits.  (Round-3 verified inner loop.)
// ---------------------------------------------------------------------------
__global__ __launch_bounds__(256)
void scan_k(bfu* __restrict__ states, size_t st_str,
            const float* __restrict__ acum_g, size_t ac_str)
{
  int di  = blockIdx.x >> 9;
  int bid = blockIdx.x & 511;
  bfu* statesd = states + (size_t)di * st_str;
  const float* acumd = acum_g + (size_t)di * ac_str;

  int eb = bid & 15, h = (bid >> 4) & 15, b = bid >> 8;
  int e = eb * 512 + threadIdx.x * 2;
  bfu* p0 = statesd + ((size_t)(b * NCHUNKC) * NHEADSC + h) * 8192 + e;
  const float* ac = acumd + ((b * NCHUNKC) * NHEADSC + h) * 64 + 63;
  const size_t cstride = (size_t)NHEADSC * 8192;
  const int astride = NHEADSC * 64;

  float pre0 = 0.f, pre1 = 0.f;
  uint raw = *(const uint*)p0;
  float dcur = expf(ac[0]);
  for (int c = 0; c < NCHUNKC; ++c) {
    uint raw_next = 0; float dnext = 0.f;
    if (c < NCHUNKC - 1) {
      raw_next = *(const uint*)(p0 + (c + 1) * cstride);
      dnext = expf(ac[(c + 1) * astride]);
    }
    float v0 = b2f((bfu)(raw & 0xffff));
    float v1 = b2f((bfu)(raw >> 16));
    uint packed = (uint)f2b(pre0) | ((uint)f2b(pre1) << 16);
    *(uint*)(p0 + c * cstride) = packed;
    pre0 = v0 + dcur * pre0;
    pre1 = v1 + dcur * pre1;
    raw = raw_next; dcur = dnext;
  }
}

// ---------------------------------------------------------------------------
// MFMA Y: per (b,c) block, 8 heads/block.  Dir-batched: grid 512*ndir.
// Writes into ycat[m][D_CAT] at column offset dir*1024 (single-GEMM fusion).
// (Round-7 verified form.)
// ---------------------------------------------------------------------------
__global__ __launch_bounds__(256)
void y_mfma_k(const bfu* __restrict__ xBC, size_t xbc_str,
              const bfu* __restrict__ states, size_t st_str,
              const float* __restrict__ acum_g, const float* __restrict__ dt_g,
              size_t ac_str,
              const float* __restrict__ D_skip, bfu* __restrict__ ycat, int dir_lo)
{
  __shared__ bfu smem[30976];
  bfu* Cs  = smem;                      // 64 x 136
  bfu* Bsc = smem + 8704;               // 64 x 136 (B tile; sc overlays)
  bfu* Ps  = smem + 17408;              // 64 x 136
  bfu* xhT = smem + 26112;              // 64 x 72
  float* acumH = (float*)(smem + 30720);
  float* dtH   = acumH + 64;

  int di  = blockIdx.x >> 9;
  int dir = dir_lo + di;
  const bfu* xBCd = xBC + (size_t)di * xbc_str;
  const bfu* statesd = states + (size_t)di * st_str;
  const float* acumd = acum_g + (size_t)di * ac_str;
  const float* dtgd  = dt_g   + (size_t)di * ac_str;

  int bid = blockIdx.x & 511;
  int hb = bid >> 8;
  int c = bid & 127, b = (bid >> 7) & 1;
  int tid = threadIdx.x, lane = tid & 63;
  int w = tid >> 6, q = lane >> 4, t = lane & 15;

#pragma unroll
  for (int r = 0; r < 8; ++r) {
    int qq = tid + r * 256;
    int row = qq >> 5, grp = qq & 31;
    const bfu* src = xBCd + (size_t)pos_of(b, c, row, dir) * CONV_DIMC;
    *(ushort4*)(Cs  + row * 136 + grp * 4) = *(const ushort4*)(src + 1152 + grp * 4);
    *(ushort4*)(Bsc + row * 136 + grp * 4) = *(const ushort4*)(src + 1024 + grp * 4);
  }
  __syncthreads();

  bf16x8 af[4];
#pragma unroll
  for (int ks = 0; ks < 4; ++ks)
    af[ks] = *(const bf16x8*)(Cs + (w * 16 + t) * 136 + ks * 32 + q * 8);

  f32x4 sacc[4];
#pragma unroll
  for (int j = 0; j < 4; ++j) sacc[j] = (f32x4){0.f, 0.f, 0.f, 0.f};
#pragma unroll
  for (int ks = 0; ks < 4; ++ks)
#pragma unroll
    for (int j = 0; j < 4; ++j) {
      bf16x8 bf = *(const bf16x8*)(Bsc + (j * 16 + t) * 136 + ks * 32 + q * 8);
      sacc[j] = __builtin_amdgcn_mfma_f32_16x16x32_bf16(af[ks], bf, sacc[j], 0, 0, 0);
    }

  for (int i = 0; i < 8; ++i) {
    int h = hb * 8 + i;
    __syncthreads();
    size_t pbase = ((size_t)(b * NCHUNKC + c) * NHEADSC + h) * 8192;
#pragma unroll
    for (int r = 0; r < 8; ++r) {
      int qq = tid + r * 256;
      int row = qq >> 5, grp = qq & 31;
      *(ushort4*)(Ps + row * 136 + grp * 4) =
          *(const ushort4*)(statesd + pbase + row * 128 + grp * 4);
    }
#pragma unroll
    for (int r = 0; r < 4; ++r) {
      int qq = tid + r * 256;
      int l = qq & 63, pg = qq >> 6;
      ushort4 v = *(const ushort4*)(xBCd + (size_t)pos_of(b, c, l, dir) * CONV_DIMC + h * 64 + pg * 4);
      xhT[(pg * 4 + 0) * 72 + l] = v.x; xhT[(pg * 4 + 1) * 72 + l] = v.y;
      xhT[(pg * 4 + 2) * 72 + l] = v.z; xhT[(pg * 4 + 3) * 72 + l] = v.w;
    }
    if (tid < 64) {
      int gi = ((b * NCHUNKC + c) * NHEADSC + h) * 64 + tid;
      acumH[tid] = acumd[gi]; dtH[tid] = dtgd[gi];
    }
    __syncthreads();

    f32x4 yacc[4];
#pragma unroll
    for (int j = 0; j < 4; ++j) yacc[j] = (f32x4){0.f, 0.f, 0.f, 0.f};
#pragma unroll
    for (int ks = 0; ks < 4; ++ks)
#pragma unroll
      for (int j = 0; j < 4; ++j) {
        bf16x8 bP = *(const bf16x8*)(Ps + (j * 16 + t) * 136 + ks * 32 + q * 8);
        yacc[j] = __builtin_amdgcn_mfma_f32_16x16x32_bf16(af[ks], bP, yacc[j], 0, 0, 0);
      }

    float Dh = D_skip[h];
    bfu* sc = Bsc;
#pragma unroll
    for (int j = 0; j < 4; ++j)
#pragma unroll
      for (int r = 0; r < 4; ++r) {
        int l = w * 16 + q * 4 + r, s = j * 16 + t;
        float v = 0.f;
        if (s <= l) v = sacc[j][r] * expf(acumH[l] - acumH[s]) * dtH[s];
        if (s == l) v += Dh;
        sc[l * 72 + s] = f2b(v);
      }

    f32x4 acc2[4];
    float dec[4];
#pragma unroll
    for (int r = 0; r < 4; ++r) dec[r] = expf(acumH[w * 16 + q * 4 + r]);
#pragma unroll
    for (int j = 0; j < 4; ++j)
#pragma unroll
      for (int r = 0; r < 4; ++r) acc2[j][r] = yacc[j][r] * dec[r];

#pragma unroll
    for (int ks = 0; ks < 2; ++ks) {
      bf16x8 asc = *(const bf16x8*)(sc + (w * 16 + t) * 72 + ks * 32 + q * 8);
#pragma unroll
      for (int j = 0; j < 4; ++j) {
        bf16x8 bx = *(const bf16x8*)(xhT + (j * 16 + t) * 72 + ks * 32 + q * 8);
        acc2[j] = __builtin_amdgcn_mfma_f32_16x16x32_bf16(asc, bx, acc2[j], 0, 0, 0);
      }
    }

#pragma unroll
    for (int j = 0; j < 4; ++j)
#pragma unroll
      for (int r = 0; r < 4; ++r) {
        int l = w * 16 + q * 4 + r, p = j * 16 + t;
        ycat[(size_t)pos_of(b, c, l, dir) * D_CAT + dir * 1024 + h * 64 + p] =
            f2b(acc2[j][r]);
      }
  }
}

// ---------------------------------------------------------------------------
// Gating (y *= silu(z)) + RMSNorm over 1024 + norm_w, in place on the dir
// half of ycat (bf16).  Dir-batched: grid 16384*ndir.
// ---------------------------------------------------------------------------
__global__ __launch_bounds__(256)
void norm_k(bfu* __restrict__ ycat, const bfu* __restrict__ zx,
            const float* __restrict__ norm_w, int dir_lo)
{
  int di  = blockIdx.x >> 14;
  int dir = dir_lo + di;
  int m = blockIdx.x & 16383, tid = threadIdx.x;
  bfu* yp = ycat + (size_t)m * D_CAT + dir * 1024 + tid * 4;
  float4 y = ld4(yp);
  float4 z = ld4(zx + (size_t)m * D_PROJC + tid * 4);
  float4 g;
  g.x = y.x * silu_(z.x); g.y = y.y * silu_(z.y);
  g.z = y.z * silu_(z.z); g.w = y.w * silu_(z.w);
  float ss = g.x * g.x + g.y * g.y + g.z * g.z + g.w * g.w;
#pragma unroll
  for (int off = 32; off >= 1; off >>= 1) ss += __shfl_xor(ss, off);
  __shared__ float red[4];
  int wid = tid >> 6;
  if ((tid & 63) == 0) red[wid] = ss;
  __syncthreads();
  float tot = red[0] + red[1] + red[2] + red[3];
  float scale = rsqrtf(tot * (1.f / 1024.f) + 1e-5f);
  float4 w = *(const float4*)(norm_w + tid * 4);
  g.x *= scale * w.x; g.y *= scale * w.y; g.z *= scale * w.z; g.w *= scale * w.w;
  st4(yp, g);
}

// ---------------------------------------------------------------------------
extern "C" void kernel_launch(void* const* d_in, const int* in_sizes, int n_in,
                              void* d_out, int out_size, void* d_ws, size_t ws_size,
                              hipStream_t stream)
{
  const float* x         = (const float*)d_in[0];
  const float* in_proj_w = (const float*)d_in[1];
  const float* conv_w    = (const float*)d_in[2];
  const float* conv_b    = (const float*)d_in[3];
  const float* dt_bias   = (const float*)d_in[4];
  const float* A_log     = (const float*)d_in[5];
  const float* D_skip    = (const float*)d_in[6];
  const float* norm_w    = (const float*)d_in[7];
  const float* ssm_out_w = (const float*)d_in[8];
  const float* fuse_w    = (const float*)d_in[9];
  const float* fuse_b    = (const float*)d_in[10];
  float* out = (float*)d_out;

  const size_t ZX_E  = (size_t)M_ROWS * D_PROJC;     // 38,010,880
  const size_t XBC_E = (size_t)M_ROWS * CONV_DIMC;   // 20,971,520
  const size_t ST_E  = 33554432;
  const size_t YC_E  = (size_t)M_ROWS * D_CAT;       // 33,554,432
  const size_t AC_E  = 262144;                       // f32 elems

  // batched (ndir=2) layout needs ~353 MiB; fall back to shared buffers
  // (ndir=1, two sequential passes) if the workspace is smaller.
  size_t need2 = (ZX_E + 2 * XBC_E + 2 * ST_E + YC_E + 2 * 524288 + 1048576) * 2
               + 4 * AC_E * 4;
  const int nd = (ws_size >= need2) ? 2 : 1;

  bfu* zx     = (bfu*)d_ws;
  bfu* xBC    = zx + ZX_E;
  bfu* states = xBC + (size_t)nd * XBC_E;
  bfu* ycat   = states + (size_t)nd * ST_E;
  float* acum = (float*)(ycat + YC_E);
  float* dtg  = acum + (size_t)nd * AC_E;
  bfu* ssmTb  = (bfu*)(dtg + (size_t)nd * AC_E);     // 1024 x 512 bf16
  bfu* fuseA  = ssmTb + 524288;                      // 1024 x 512 bf16
  bfu* wcmb   = fuseA + 524288;                      // 1024 x 1024 bf16
  // transient aliases inside the states region (dead before states_mfma_k):
  bfu* xb = states;                    // 16384 x 512 bf16
  bfu* wb = states + 8388608;          // 2560  x 512 bf16 (padded for 256-tile)

  const size_t xbc_str = (nd == 2) ? XBC_E : 0;
  const size_t st_str  = (nd == 2) ? ST_E  : 0;
  const size_t ac_str  = (nd == 2) ? AC_E  : 0;

  cvt_x_k<<<8192, 256, 0, stream>>>(x, xb);
  cvt_w_k<<<1280, 256, 0, stream>>>(in_proj_w, wb);     // rows 2320..2559 zero
  transpose_k<<<2048, 256, 0, stream>>>(ssm_out_w, ssmTb);
  cvt_fuse_k<<<512, 256, 0, stream>>>(fuse_w, fuseA);

  // wcmb[(o*2+dir)][j] = sum_k fuse_w[o, dir*512+k] * ssm_out_w[k, j]
  mfma_nt<<<dim3(8, 8), 256, 0, stream>>>(
      fuseA, 512, ssmTb, 512, wcmb, 1024, 1024, 512, nullptr, 0);

  // in_proj: zx = x @ in_proj_w^T  (8-phase 256x128 pipeline, 1280 blocks
  // = exactly 5 full CU rounds at 1 block/CU)
  mfma_nt_8p<<<dim3(20, 64), 512, 0, stream>>>(
      xb, 512, wb, 512, zx, D_PROJC, D_PROJC, 512);

  for (int dl = 0; dl < 2; dl += nd) {
    conv_k<<<dim3(5, 2048 * nd), 256, 0, stream>>>(
        zx, conv_w, conv_b, xBC, xbc_str, dl);
    states_mfma_k<<<512 * nd, 256, 0, stream>>>(
        zx, xBC, xbc_str, dt_bias, A_log, acum, dtg, ac_str, states, st_str, dl);
    scan_k<<<512 * nd, 256, 0, stream>>>(states, st_str, acum, ac_str);
    y_mfma_k<<<512 * nd, 256, 0, stream>>>(
        xBC, xbc_str, states, st_str, acum, dtg, ac_str, D_skip, ycat, dl);
    norm_k<<<16384 * nd, 256, 0, stream>>>(ycat, zx, norm_w, dl);
  }

  // single fused output GEMM: out = ycat @ wcmb^T + fuse_b  (K = 2048)
  mfma_nt<<<dim3(4, 128), 256, 0, stream>>>(
      ycat, D_CAT, wcmb, D_CAT, out, 512, 512, D_CAT, fuse_b, 1);
}

// Round 11
// 504.231 us; speedup vs baseline: 1.1899x; 1.0059x over previous
//
#include <hip/hip_runtime.h>
#include <cstddef>

// Problem constants
#define B_SZ     2
#define L_SEQ    8192
#define D_INNERC 1024
#define D_CAT    2048         // concat of fwd|rev y halves
#define NHEADSC  16
#define CHUNKC   64
#define NCHUNKC  128          // L_SEQ / CHUNK
#define CONV_DIMC 1280
#define D_PROJC  2320
#define M_ROWS   16384        // B_SZ * L_SEQ

typedef unsigned short bfu;   // raw bf16 bits

using bf16x8 = __attribute__((ext_vector_type(8))) short;
using f32x4  = __attribute__((ext_vector_type(4))) float;

__device__ __forceinline__ float silu_(float v) { return v / (1.f + expf(-v)); }

__device__ __forceinline__ float b2f(bfu u) {
  return __uint_as_float((unsigned)u << 16);
}
__device__ __forceinline__ bfu f2b(float f) {
  unsigned x = __float_as_uint(f);
  return (bfu)((x + 0x7fffu + ((x >> 16) & 1u)) >> 16);   // RNE
}

__device__ __forceinline__ float4 ld4(const float* p) { return *(const float4*)p; }
__device__ __forceinline__ float4 ld4(const bfu* p) {
  ushort4 u = *(const ushort4*)p;
  float4 f;
  f.x = b2f(u.x); f.y = b2f(u.y); f.z = b2f(u.z); f.w = b2f(u.w);
  return f;
}
__device__ __forceinline__ void st4(float* p, float4 v) { *(float4*)p = v; }
__device__ __forceinline__ void st4(bfu* p, float4 v) {
  ushort4 u;
  u.x = f2b(v.x); u.y = f2b(v.y); u.z = f2b(v.z); u.w = f2b(v.w);
  *(ushort4*)p = u;
}

__device__ __forceinline__ void gl_lds16(const bfu* g, bfu* l) {
  __builtin_amdgcn_global_load_lds(
      (const __attribute__((address_space(1))) unsigned int*)g,
      (__attribute__((address_space(3))) unsigned int*)l, 16, 0, 0);
}

__device__ __forceinline__ int pos_of(int b, int c, int l, int dir) {
  int t = c * CHUNKC + l;
  return dir ? (b * L_SEQ + (L_SEQ - 1) - t) : (b * L_SEQ + t);
}

// ---------------------------------------------------------------------------
// MFMA GEMM (NT): C[m][n] = sum_k A[m][k] * Bw[n][k].  A,B bf16, K-contig.
// 128x128 tile, BK=64 (K % 64 == 0), 256 thr = 4 waves 2x2, 4x4x(2 k-step)
// MFMAs of 16x16x32.  Used only for the small wcmb GEMM now.
// mode: 0 -> store bf16;  1 -> store f32 (+bias)
// ---------------------------------------------------------------------------
__global__ __launch_bounds__(256)
void mfma_nt(const bfu* __restrict__ A, int lda,
             const bfu* __restrict__ Bw, int ldb,
             void* __restrict__ Cv, int ldc,
             int N, int K, const float* __restrict__ bias, int mode)
{
  __shared__ bfu sh[16384];           // 32 KB: As | Bs, reused by epilogue
  bfu* As = sh;                       // 128 x 64
  bfu* Bs = sh + 8192;                // 128 x 64
  const int tid  = threadIdx.x;
  const int lane = tid & 63;
  const int wave = __builtin_amdgcn_readfirstlane(tid >> 6);
  const int wm = wave & 1, wn = wave >> 1;

  const int num_n = gridDim.x;
  const int flat  = blockIdx.y * num_n + blockIdx.x;
  const int xcd   = flat & 7;
  const int g     = flat >> 3;
  const int n0 = (g % num_n) * 128;
  const int m0 = ((g / num_n) * 8 + xcd) * 128;

  f32x4 acc[4][4];
#pragma unroll
  for (int i = 0; i < 4; ++i)
#pragma unroll
    for (int j = 0; j < 4; ++j)
      acc[i][j] = (f32x4){0.f, 0.f, 0.f, 0.f};

  const int ro   = lane >> 3;          // row within 8-row staging slice
  const int slot = lane & 7;           // stored colgroup slot

  for (int k0 = 0; k0 < K; k0 += 64) {
    __syncthreads();
    // each wave stages rows [wave*32, wave*32+32) of A and B, 8 rows/call
#pragma unroll
    for (int si = 0; si < 4; ++si) {
      int r = wave * 32 + si * 8 + ro;
      int cg = slot ^ (r & 7);
      gl_lds16(A  + (size_t)(m0 + r) * lda + k0 + cg * 8, As + (wave * 32 + si * 8) * 64);
      gl_lds16(Bw + (size_t)(n0 + r) * ldb + k0 + cg * 8, Bs + (wave * 32 + si * 8) * 64);
    }
    __syncthreads();

#pragma unroll
    for (int ks = 0; ks < 2; ++ks) {
      bf16x8 af[4], bfr[4];
#pragma unroll
      for (int i = 0; i < 4; ++i) {
        int ra = wm * 64 + i * 16 + (lane & 15);
        int ca = (ks * 4 + (lane >> 4)) ^ (ra & 7);
        af[i] = *(const bf16x8*)(As + ra * 64 + ca * 8);
        int rb = wn * 64 + i * 16 + (lane & 15);
        int cb = (ks * 4 + (lane >> 4)) ^ (rb & 7);
        bfr[i] = *(const bf16x8*)(Bs + rb * 64 + cb * 8);
      }
#pragma unroll
      for (int i = 0; i < 4; ++i)
#pragma unroll
        for (int j = 0; j < 4; ++j)
          acc[i][j] = __builtin_amdgcn_mfma_f32_16x16x32_bf16(af[i], bfr[j], acc[i][j], 0, 0, 0);
    }
  }

  // ---- epilogue: repack through LDS, coalesced dwordx4 stores ----
  // C/D layout: col = lane&15, row = (lane>>4)*4 + reg
  __syncthreads();
  if (mode == 0) {
    // whole 128x128 bf16 tile fits in 32 KB
#pragma unroll
    for (int i = 0; i < 4; ++i)
#pragma unroll
      for (int j = 0; j < 4; ++j)
#pragma unroll
        for (int r = 0; r < 4; ++r) {
          int ml = wm * 64 + i * 16 + (lane >> 4) * 4 + r;
          int nl = wn * 64 + j * 16 + (lane & 15);
          sh[ml * 128 + nl] = f2b(acc[i][j][r]);
        }
    __syncthreads();
    bfu* Cb = (bfu*)Cv;
#pragma unroll
    for (int rr = 0; rr < 8; ++rr) {
      int idx = rr * 256 + tid;            // 8-elem group id, 0..2047
      int row = idx >> 4, co = (idx & 15) * 8;
      if (n0 + co < N) {                   // N is 8-aligned
        *(ulonglong2*)(Cb + (size_t)(m0 + row) * ldc + n0 + co) =
            *(const ulonglong2*)(sh + row * 128 + co);
      }
    }
  } else {
    float* Cf = (float*)Cv;
    float* shf = (float*)sh;               // 64 rows x 128 f32 per pass
#pragma unroll
    for (int p = 0; p < 2; ++p) {
      if (wm == p) {
#pragma unroll
        for (int i = 0; i < 4; ++i)
#pragma unroll
          for (int j = 0; j < 4; ++j)
#pragma unroll
            for (int r = 0; r < 4; ++r) {
              int ml = i * 16 + (lane >> 4) * 4 + r;   // 0..63
              int nl = wn * 64 + j * 16 + (lane & 15);
              shf[ml * 128 + nl] = acc[i][j][r];
            }
      }
      __syncthreads();
#pragma unroll
      for (int rr = 0; rr < 8; ++rr) {
        int idx = rr * 256 + tid;          // float4 group id, 0..2047
        int row = idx >> 5, co = (idx & 31) * 4;
        int n = n0 + co;
        if (n < N) {
          float4 v = *(float4*)(shf + row * 128 + co);
          float* cp = Cf + (size_t)(m0 + p * 64 + row) * ldc + n;
          if (bias) {
            v.x += bias[n]; v.y += bias[n + 1]; v.z += bias[n + 2]; v.w += bias[n + 3];
          }
          *(float4*)cp = v;
        }
      }
      __syncthreads();
    }
  }
}

// ---------------------------------------------------------------------------
// 8-phase 256x128 MFMA GEMM (NT).  512 thr = 8 waves (4M x 2N), BK=64,
// K % 128 == 0, M % 256 == 0, N-tiles of 128.  LDS 96 KB: dbuf A (2x32KB)
// + dbuf B (2x16KB).  Counted vmcnt(2) at phases 4/8 (invariant: next
// B-tile in flight across iterations); vmcnt(0) only at last iter phase 4.
// mode: 0 -> store bf16;  1 -> store f32 (+bias), two 128-row LDS passes.
// ---------------------------------------------------------------------------
__global__ __launch_bounds__(512)
void mfma_nt_8p(const bfu* __restrict__ A, int lda,
                const bfu* __restrict__ Bw, int ldb,
                void* __restrict__ Cv, int ldc, int N, int K,
                const float* __restrict__ bias, int mode)
{
  __shared__ bfu sh[49152];            // 96 KB; epilogue reuses
  bfu* As0 = sh;                        // A tile kt   (even), 256x64
  bfu* As1 = sh + 16384;                // A tile kt+1 (odd),  256x64
  bfu* Bs0 = sh + 32768;                // B tile kt   128x64
  bfu* Bs1 = sh + 40960;                // B tile kt+1 128x64

  const int tid  = threadIdx.x;
  const int lane = tid & 63;
  const int w    = __builtin_amdgcn_readfirstlane(tid >> 6);
  const int wm = w & 3, wn = w >> 2;    // 4 x 2 wave grid
  const int q = lane >> 4, t = lane & 15;

  const int num_n = gridDim.x;
  const int flat  = blockIdx.y * num_n + blockIdx.x;
  const int xcd   = flat & 7;
  const int g     = flat >> 3;
  const int n0 = (g % num_n) * 128;
  const int m0 = ((g / num_n) * 8 + xcd) * 256;

  // stage 128 rows x 64 cols (16 KB): 2 gl_lds per thread.
  auto STG = [&](const bfu* __restrict__ X, int ldx, int x0, int kt, int h,
                 bfu* dst) {
#pragma unroll
    for (int ci = 0; ci < 2; ++ci) {
      int rb = h * 128 + ci * 64 + w * 8;          // wave-uniform row base
      int r  = rb + (lane >> 3);
      int cg = (lane & 7) ^ (r & 7);
      gl_lds16(X + (size_t)(x0 + r) * ldx + kt * 64 + cg * 8, dst + rb * 64);
    }
  };
  auto FR = [&](const bfu* tile, int R, int gg) -> bf16x8 {
    return *(const bf16x8*)(tile + R * 64 + ((gg ^ (R & 7)) * 8));
  };

  f32x4 acc[4][4];
#pragma unroll
  for (int i = 0; i < 4; ++i)
#pragma unroll
    for (int j = 0; j < 4; ++j)
      acc[i][j] = (f32x4){0.f, 0.f, 0.f, 0.f};

  // prologue: B(0), A(0) both halves, B(1).  Need tile0 landed; keep B(1)
  // (2 newest loads) in flight -> vmcnt(2).
  STG(Bw, ldb, n0, 0, 0, Bs0);
  STG(A,  lda, m0, 0, 0, As0); STG(A,  lda, m0, 0, 1, As0);
  STG(Bw, ldb, n0, 1, 0, Bs1);
  asm volatile("s_waitcnt vmcnt(2)" ::: "memory");
  __builtin_amdgcn_s_barrier();

  const int nIter = K >> 7;            // K % 128 == 0
  bf16x8 bfr[4][2];
  for (int it = 0; it < nIter; ++it) {
    const int kt = it * 2;
    const bool last = (it == nIter - 1);

    // ---- K-tile kt (As0/Bs0), phases 0..3 ----
    // entering in-flight: B(kt+1) [2 loads]
#pragma unroll
    for (int p = 0; p < 4; ++p) {
      bf16x8 af[2];
#pragma unroll
      for (int ks = 0; ks < 2; ++ks)
        af[ks] = FR(As0, wm * 64 + p * 16 + t, ks * 4 + q);
      if (p == 0) {
#pragma unroll
        for (int j = 0; j < 4; ++j)
#pragma unroll
          for (int ks = 0; ks < 2; ++ks)
            bfr[j][ks] = FR(Bs0, wn * 64 + j * 16 + t, ks * 4 + q);
      }
      if (p == 0)          STG(A,  lda, m0, kt + 1, 0, As1);
      if (p == 1)          STG(A,  lda, m0, kt + 1, 1, As1);
      if (p == 2 && !last) STG(Bw, ldb, n0, kt + 2, 0, Bs0);
      if (p == 3) {
        // outstanding: [B(kt+1)] + A(kt+1) (+ B(kt+2) if !last)
        if (last) asm volatile("s_waitcnt vmcnt(0)" ::: "memory");
        else      asm volatile("s_waitcnt vmcnt(2)" ::: "memory");
      }
      __builtin_amdgcn_s_barrier();
      __builtin_amdgcn_s_setprio(1);
#pragma unroll
      for (int ks = 0; ks < 2; ++ks)
#pragma unroll
        for (int j = 0; j < 4; ++j)
          acc[p][j] = __builtin_amdgcn_mfma_f32_16x16x32_bf16(
              af[ks], bfr[j][ks], acc[p][j], 0, 0, 0);
      __builtin_amdgcn_s_setprio(0);
      __builtin_amdgcn_s_barrier();
    }

    // ---- K-tile kt+1 (As1/Bs1), phases 4..7 ----
    // entering in-flight: B(kt+2) [2 loads] (none if last)
#pragma unroll
    for (int p = 0; p < 4; ++p) {
      bf16x8 af[2];
#pragma unroll
      for (int ks = 0; ks < 2; ++ks)
        af[ks] = FR(As1, wm * 64 + p * 16 + t, ks * 4 + q);
      if (p == 0) {
#pragma unroll
        for (int j = 0; j < 4; ++j)
#pragma unroll
          for (int ks = 0; ks < 2; ++ks)
            bfr[j][ks] = FR(Bs1, wn * 64 + j * 16 + t, ks * 4 + q);
      }
      if (p == 0 && !last) STG(A,  lda, m0, kt + 2, 0, As0);
      if (p == 1 && !last) STG(A,  lda, m0, kt + 2, 1, As0);
      if (p == 2 && !last) STG(Bw, ldb, n0, kt + 3, 0, Bs1);
      if (p == 3 && !last) asm volatile("s_waitcnt vmcnt(2)" ::: "memory");
      __builtin_amdgcn_s_barrier();
      __builtin_amdgcn_s_setprio(1);
#pragma unroll
      for (int ks = 0; ks < 2; ++ks)
#pragma unroll
        for (int j = 0; j < 4; ++j)
          acc[p][j] = __builtin_amdgcn_mfma_f32_16x16x32_bf16(
              af[ks], bfr[j][ks], acc[p][j], 0, 0, 0);
      __builtin_amdgcn_s_setprio(0);
      __builtin_amdgcn_s_barrier();
    }
  }

  // ---- epilogue ----
  // C/D layout: col = lane&15, row = (lane>>4)*4 + reg
  __syncthreads();
  if (mode == 0) {
    // 256x128 bf16 tile (64 KB of the 96)
#pragma unroll
    for (int i = 0; i < 4; ++i)
#pragma unroll
      for (int j = 0; j < 4; ++j)
#pragma unroll
        for (int r = 0; r < 4; ++r) {
          int ml = wm * 64 + i * 16 + q * 4 + r;
          int nl = wn * 64 + j * 16 + t;
          sh[ml * 128 + nl] = f2b(acc[i][j][r]);
        }
    __syncthreads();
    bfu* Cb = (bfu*)Cv;
#pragma unroll
    for (int rr = 0; rr < 8; ++rr) {
      int idx = rr * 512 + tid;            // 8-elem group id, 0..4095
      int row = idx >> 4, co = (idx & 15) * 8;
      if (n0 + co < N) {                   // N is 8-aligned
        *(ulonglong2*)(Cb + (size_t)(m0 + row) * ldc + n0 + co) =
            *(const ulonglong2*)(sh + row * 128 + co);
      }
    }
  } else {
    // f32 + bias: two passes of 128 rows x 128 f32 (64 KB each)
    float* Cf = (float*)Cv;
    float* shf = (float*)sh;
#pragma unroll
    for (int p = 0; p < 2; ++p) {
      if ((wm >> 1) == p) {
#pragma unroll
        for (int i = 0; i < 4; ++i)
#pragma unroll
          for (int j = 0; j < 4; ++j)
#pragma unroll
            for (int r = 0; r < 4; ++r) {
              int ml = (wm & 1) * 64 + i * 16 + q * 4 + r;   // 0..127
              int nl = wn * 64 + j * 16 + t;
              shf[ml * 128 + nl] = acc[i][j][r];
            }
      }
      __syncthreads();
#pragma unroll
      for (int rr = 0; rr < 8; ++rr) {
        int idx = rr * 512 + tid;          // float4 group id, 0..4095
        int row = idx >> 5, co = (idx & 31) * 4;
        int n = n0 + co;
        if (n < N) {
          float4 v = *(float4*)(shf + row * 128 + co);
          float* cp = Cf + (size_t)(m0 + p * 128 + row) * ldc + n;
          if (bias) {
            v.x += bias[n]; v.y += bias[n + 1]; v.z += bias[n + 2]; v.w += bias[n + 3];
          }
          *(float4*)cp = v;
        }
      }
      __syncthreads();
    }
  }
}

// ---------------------------------------------------------------------------
// setup converts (all fp32 -> bf16)
// ---------------------------------------------------------------------------
__global__ __launch_bounds__(256)
void cvt_x_k(const float* __restrict__ in, bfu* __restrict__ out)
{
  int q = blockIdx.x * 256 + threadIdx.x;
  st4(out + (size_t)q * 4, ld4(in + (size_t)q * 4));
}

__global__ __launch_bounds__(256)
void cvt_w_k(const float* __restrict__ in, bfu* __restrict__ out)
{
  int q = blockIdx.x * 256 + threadIdx.x;
  int row = q >> 7, c4 = (q & 127) << 2;
  float4 v = {0.f, 0.f, 0.f, 0.f};
  if (row < D_PROJC) v = ld4(in + (size_t)row * 512 + c4);
  st4(out + (size_t)row * 512 + c4, v);
}

// ssm_out_w (512 x 1024 f32) -> ssmTb (1024 x 512 bf16)
__global__ __launch_bounds__(256)
void transpose_k(const float* __restrict__ in, bfu* __restrict__ out)
{
  int idx = blockIdx.x * 256 + threadIdx.x;   // 0 .. 524287
  int j = idx >> 9, k = idx & 511;
  out[idx] = f2b(in[k * 1024 + j]);
}

// fuse_w (512 x 1024 f32) -> fuseA (1024 x 512 bf16), row m' = o*2 + dir
__global__ __launch_bounds__(256)
void cvt_fuse_k(const float* __restrict__ in, bfu* __restrict__ out)
{
  int q = blockIdx.x * 256 + threadIdx.x;     // 0 .. 131071 (4-elem groups)
  int m = q >> 7, kg = (q & 127) << 2;        // m' = o*2 + dir
  int o = m >> 1, dir = m & 1;
  float4 v = ld4(in + (size_t)o * 1024 + dir * 512 + kg);
  st4(out + (size_t)m * 512 + kg, v);
}

// ---------------------------------------------------------------------------
// Depthwise conv + bias + SiLU, 8 outputs per thread (taps staged in regs).
// Dir-batched: grid (5, 2048*ndir); blockIdx.y>>11 selects dir slot.
// ---------------------------------------------------------------------------
__global__ __launch_bounds__(256)
void conv_k(const bfu* __restrict__ zx, const float* __restrict__ conv_w,
            const float* __restrict__ conv_b, bfu* __restrict__ xBC,
            size_t xbc_str, int dir_lo)
{
  int di  = blockIdx.y >> 11;
  int dir = dir_lo + di;
  bfu* xBCd = xBC + (size_t)di * xbc_str;
  int ch = blockIdx.x * 256 + threadIdx.x;   // 0..1279
  int m0 = (blockIdx.y & 2047) * 8;          // global row base
  int b  = m0 >> 13, tb = m0 & (L_SEQ - 1);
  float w0 = conv_w[ch * 4 + 0], w1 = conv_w[ch * 4 + 1];
  float w2 = conv_w[ch * 4 + 2], w3 = conv_w[ch * 4 + 3];
  float cb = conv_b[ch];
  const bfu* src = zx + 1024 + ch;
  const int shift = dir ? 0 : 3;

  float v[11];
#pragma unroll
  for (int i = 0; i < 11; ++i) {
    int tt = tb + i - shift;
    v[i] = (tt >= 0 && tt < L_SEQ)
         ? b2f(src[(size_t)(b * L_SEQ + tt) * D_PROJC]) : 0.f;
  }
#pragma unroll
  for (int j = 0; j < 8; ++j) {
    float acc = cb;
    if (dir == 0) {
      acc += w0 * v[j] + w1 * v[j + 1] + w2 * v[j + 2] + w3 * v[j + 3];
    } else {
      acc += w0 * v[j + 3] + w1 * v[j + 2] + w2 * v[j + 1] + w3 * v[j];
    }
    xBCd[(size_t)(m0 + j) * CONV_DIMC + ch] = f2b(silu_(acc));
  }
}

// ---------------------------------------------------------------------------
// MFMA states: per (b,c) block, 8 heads/block.  Dir-batched: grid 512*ndir.
// T14 async-stage: head i+1's xh global loads issued into registers before
// head i's compute; consumed at next xsT write.
// ---------------------------------------------------------------------------
__global__ __launch_bounds__(256)
void states_mfma_k(const bfu* __restrict__ zx, const bfu* __restrict__ xBC,
                   size_t xbc_str,
                   const float* __restrict__ dt_bias, const float* __restrict__ A_log,
                   float* __restrict__ acum_g, float* __restrict__ dt_g,
                   size_t ac_str,
                   bfu* __restrict__ states, size_t st_str, int dir_lo)
{
  __shared__ bfu BT[128 * 72];     // [n][l]
  __shared__ bfu xsT[64 * 72];     // [p][l]
  __shared__ float scaleS[8 * 64];

  int di  = blockIdx.x >> 9;
  int dir = dir_lo + di;
  const bfu* xBCd = xBC + (size_t)di * xbc_str;
  float* acumd = acum_g + (size_t)di * ac_str;
  float* dtgd  = dt_g   + (size_t)di * ac_str;
  bfu* statesd = states + (size_t)di * st_str;

  int bid = blockIdx.x & 511;
  int hb = bid >> 8;
  int c = bid & 127, b = (bid >> 7) & 1;
  int tid = threadIdx.x, lane = tid & 63;
  int w = tid >> 6, q = lane >> 4, t = lane & 15;

#pragma unroll
  for (int rr = 0; rr < 2; ++rr) {
    int i = w + rr * 4;
    int h = hb * 8 + i;
    int l = lane;
    int pos = pos_of(b, c, l, dir);
    float dtr = b2f(zx[(size_t)pos * D_PROJC + 2304 + h]) + dt_bias[h];
    float dt = (dtr > 20.f) ? dtr : log1pf(expf(dtr));
    float a = -expf(A_log[h]) * dt;
#pragma unroll
    for (int off = 1; off < 64; off <<= 1) {
      float v = __shfl_up(a, off);
      if (l >= off) a += v;
    }
    float alast = __shfl(a, 63);
    int gi = ((b * NCHUNKC + c) * NHEADSC + h) * 64 + l;
    acumd[gi] = a; dtgd[gi] = dt;
    scaleS[i * 64 + l] = dt * expf(alast - a);
  }

#pragma unroll
  for (int r = 0; r < 8; ++r) {
    int qq = tid + r * 256;
    int l = qq & 63, ng = qq >> 6;
    ushort4 v = *(const ushort4*)(xBCd + (size_t)pos_of(b, c, l, dir) * CONV_DIMC + 1024 + ng * 4);
    BT[(ng * 4 + 0) * 72 + l] = v.x; BT[(ng * 4 + 1) * 72 + l] = v.y;
    BT[(ng * 4 + 2) * 72 + l] = v.z; BT[(ng * 4 + 3) * 72 + l] = v.w;
  }

  ushort4 xr[4];
  auto PREFX = [&](int i) {
    int h = hb * 8 + i;
#pragma unroll
    for (int r = 0; r < 4; ++r) {
      int qq = tid + r * 256;
      int l = qq & 63, pg = qq >> 6;
      xr[r] = *(const ushort4*)(xBCd + (size_t)pos_of(b, c, l, dir) * CONV_DIMC + h * 64 + pg * 4);
    }
  };
  PREFX(0);
  __syncthreads();

  for (int i = 0; i < 8; ++i) {
    int h = hb * 8 + i;
#pragma unroll
    for (int r = 0; r < 4; ++r) {
      int qq = tid + r * 256;
      int l = qq & 63, pg = qq >> 6;
      float s = scaleS[i * 64 + l];
      ushort4 v = xr[r];
      xsT[(pg * 4 + 0) * 72 + l] = f2b(b2f(v.x) * s);
      xsT[(pg * 4 + 1) * 72 + l] = f2b(b2f(v.y) * s);
      xsT[(pg * 4 + 2) * 72 + l] = f2b(b2f(v.z) * s);
      xsT[(pg * 4 + 3) * 72 + l] = f2b(b2f(v.w) * s);
    }
    if (i < 7) PREFX(i + 1);
    __syncthreads();

    bf16x8 axs[2];
#pragma unroll
    for (int ks = 0; ks < 2; ++ks)
      axs[ks] = *(const bf16x8*)(xsT + (w * 16 + t) * 72 + ks * 32 + q * 8);

    f32x4 acc[8];
#pragma unroll
    for (int j = 0; j < 8; ++j) acc[j] = (f32x4){0.f, 0.f, 0.f, 0.f};
#pragma unroll
    for (int ks = 0; ks < 2; ++ks)
#pragma unroll
      for (int j = 0; j < 8; ++j) {
        bf16x8 bB = *(const bf16x8*)(BT + (j * 16 + t) * 72 + ks * 32 + q * 8);
        acc[j] = __builtin_amdgcn_mfma_f32_16x16x32_bf16(axs[ks], bB, acc[j], 0, 0, 0);
      }

    size_t base = ((size_t)(b * NCHUNKC + c) * NHEADSC + h) * 8192;
#pragma unroll
    for (int j = 0; j < 8; ++j)
#pragma unroll
      for (int r = 0; r < 4; ++r) {
        int p = w * 16 + q * 4 + r, n = j * 16 + t;
        statesd[base + p * 128 + n] = f2b(acc[j][r]);
      }
    __syncthreads();
  }
}

// ---------------------------------------------------------------------------
// Inter-chunk scan with explicit next-chunk prefetch.  Dir-batched:
// grid 512*ndir; (b,h,eb) from low 9 bits.  (Round-3 verified inner loop.)
// ---------------------------------------------------------------------------
__global__ __launch_bounds__(256)
void scan_k(bfu* __restrict__ states, size_t st_str,
            const float* __restrict__ acum_g, size_t ac_str)
{
  int di  = blockIdx.x >> 9;
  int bid = blockIdx.x & 511;
  bfu* statesd = states + (size_t)di * st_str;
  const float* acumd = acum_g + (size_t)di * ac_str;

  int eb = bid & 15, h = (bid >> 4) & 15, b = bid >> 8;
  int e = eb * 512 + threadIdx.x * 2;
  bfu* p0 = statesd + ((size_t)(b * NCHUNKC) * NHEADSC + h) * 8192 + e;
  const float* ac = acumd + ((b * NCHUNKC) * NHEADSC + h) * 64 + 63;
  const size_t cstride = (size_t)NHEADSC * 8192;
  const int astride = NHEADSC * 64;

  float pre0 = 0.f, pre1 = 0.f;
  uint raw = *(const uint*)p0;
  float dcur = expf(ac[0]);
  for (int c = 0; c < NCHUNKC; ++c) {
    uint raw_next = 0; float dnext = 0.f;
    if (c < NCHUNKC - 1) {
      raw_next = *(const uint*)(p0 + (c + 1) * cstride);
      dnext = expf(ac[(c + 1) * astride]);
    }
    float v0 = b2f((bfu)(raw & 0xffff));
    float v1 = b2f((bfu)(raw >> 16));
    uint packed = (uint)f2b(pre0) | ((uint)f2b(pre1) << 16);
    *(uint*)(p0 + c * cstride) = packed;
    pre0 = v0 + dcur * pre0;
    pre1 = v1 + dcur * pre1;
    raw = raw_next; dcur = dnext;
  }
}

// ---------------------------------------------------------------------------
// MFMA Y: per (b,c) block, 8 heads/block.  Dir-batched: grid 512*ndir.
// Writes into ycat[m][D_CAT] at column offset dir*1024 (single-GEMM fusion).
// (Round-7 verified form.)
// ---------------------------------------------------------------------------
__global__ __launch_bounds__(256)
void y_mfma_k(const bfu* __restrict__ xBC, size_t xbc_str,
              const bfu* __restrict__ states, size_t st_str,
              const float* __restrict__ acum_g, const float* __restrict__ dt_g,
              size_t ac_str,
              const float* __restrict__ D_skip, bfu* __restrict__ ycat, int dir_lo)
{
  __shared__ bfu smem[30976];
  bfu* Cs  = smem;                      // 64 x 136
  bfu* Bsc = smem + 8704;               // 64 x 136 (B tile; sc overlays)
  bfu* Ps  = smem + 17408;              // 64 x 136
  bfu* xhT = smem + 26112;              // 64 x 72
  float* acumH = (float*)(smem + 30720);
  float* dtH   = acumH + 64;

  int di  = blockIdx.x >> 9;
  int dir = dir_lo + di;
  const bfu* xBCd = xBC + (size_t)di * xbc_str;
  const bfu* statesd = states + (size_t)di * st_str;
  const float* acumd = acum_g + (size_t)di * ac_str;
  const float* dtgd  = dt_g   + (size_t)di * ac_str;

  int bid = blockIdx.x & 511;
  int hb = bid >> 8;
  int c = bid & 127, b = (bid >> 7) & 1;
  int tid = threadIdx.x, lane = tid & 63;
  int w = tid >> 6, q = lane >> 4, t = lane & 15;

#pragma unroll
  for (int r = 0; r < 8; ++r) {
    int qq = tid + r * 256;
    int row = qq >> 5, grp = qq & 31;
    const bfu* src = xBCd + (size_t)pos_of(b, c, row, dir) * CONV_DIMC;
    *(ushort4*)(Cs  + row * 136 + grp * 4) = *(const ushort4*)(src + 1152 + grp * 4);
    *(ushort4*)(Bsc + row * 136 + grp * 4) = *(const ushort4*)(src + 1024 + grp * 4);
  }
  __syncthreads();

  bf16x8 af[4];
#pragma unroll
  for (int ks = 0; ks < 4; ++ks)
    af[ks] = *(const bf16x8*)(Cs + (w * 16 + t) * 136 + ks * 32 + q * 8);

  f32x4 sacc[4];
#pragma unroll
  for (int j = 0; j < 4; ++j) sacc[j] = (f32x4){0.f, 0.f, 0.f, 0.f};
#pragma unroll
  for (int ks = 0; ks < 4; ++ks)
#pragma unroll
    for (int j = 0; j < 4; ++j) {
      bf16x8 bf = *(const bf16x8*)(Bsc + (j * 16 + t) * 136 + ks * 32 + q * 8);
      sacc[j] = __builtin_amdgcn_mfma_f32_16x16x32_bf16(af[ks], bf, sacc[j], 0, 0, 0);
    }

  for (int i = 0; i < 8; ++i) {
    int h = hb * 8 + i;
    __syncthreads();
    size_t pbase = ((size_t)(b * NCHUNKC + c) * NHEADSC + h) * 8192;
#pragma unroll
    for (int r = 0; r < 8; ++r) {
      int qq = tid + r * 256;
      int row = qq >> 5, grp = qq & 31;
      *(ushort4*)(Ps + row * 136 + grp * 4) =
          *(const ushort4*)(statesd + pbase + row * 128 + grp * 4);
    }
#pragma unroll
    for (int r = 0; r < 4; ++r) {
      int qq = tid + r * 256;
      int l = qq & 63, pg = qq >> 6;
      ushort4 v = *(const ushort4*)(xBCd + (size_t)pos_of(b, c, l, dir) * CONV_DIMC + h * 64 + pg * 4);
      xhT[(pg * 4 + 0) * 72 + l] = v.x; xhT[(pg * 4 + 1) * 72 + l] = v.y;
      xhT[(pg * 4 + 2) * 72 + l] = v.z; xhT[(pg * 4 + 3) * 72 + l] = v.w;
    }
    if (tid < 64) {
      int gi = ((b * NCHUNKC + c) * NHEADSC + h) * 64 + tid;
      acumH[tid] = acumd[gi]; dtH[tid] = dtgd[gi];
    }
    __syncthreads();

    f32x4 yacc[4];
#pragma unroll
    for (int j = 0; j < 4; ++j) yacc[j] = (f32x4){0.f, 0.f, 0.f, 0.f};
#pragma unroll
    for (int ks = 0; ks < 4; ++ks)
#pragma unroll
      for (int j = 0; j < 4; ++j) {
        bf16x8 bP = *(const bf16x8*)(Ps + (j * 16 + t) * 136 + ks * 32 + q * 8);
        yacc[j] = __builtin_amdgcn_mfma_f32_16x16x32_bf16(af[ks], bP, yacc[j], 0, 0, 0);
      }

    float Dh = D_skip[h];
    bfu* sc = Bsc;
#pragma unroll
    for (int j = 0; j < 4; ++j)
#pragma unroll
      for (int r = 0; r < 4; ++r) {
        int l = w * 16 + q * 4 + r, s = j * 16 + t;
        float v = 0.f;
        if (s <= l) v = sacc[j][r] * expf(acumH[l] - acumH[s]) * dtH[s];
        if (s == l) v += Dh;
        sc[l * 72 + s] = f2b(v);
      }

    f32x4 acc2[4];
    float dec[4];
#pragma unroll
    for (int r = 0; r < 4; ++r) dec[r] = expf(acumH[w * 16 + q * 4 + r]);
#pragma unroll
    for (int j = 0; j < 4; ++j)
#pragma unroll
      for (int r = 0; r < 4; ++r) acc2[j][r] = yacc[j][r] * dec[r];

#pragma unroll
    for (int ks = 0; ks < 2; ++ks) {
      bf16x8 asc = *(const bf16x8*)(sc + (w * 16 + t) * 72 + ks * 32 + q * 8);
#pragma unroll
      for (int j = 0; j < 4; ++j) {
        bf16x8 bx = *(const bf16x8*)(xhT + (j * 16 + t) * 72 + ks * 32 + q * 8);
        acc2[j] = __builtin_amdgcn_mfma_f32_16x16x32_bf16(asc, bx, acc2[j], 0, 0, 0);
      }
    }

#pragma unroll
    for (int j = 0; j < 4; ++j)
#pragma unroll
      for (int r = 0; r < 4; ++r) {
        int l = w * 16 + q * 4 + r, p = j * 16 + t;
        ycat[(size_t)pos_of(b, c, l, dir) * D_CAT + dir * 1024 + h * 64 + p] =
            f2b(acc2[j][r]);
      }
  }
}

// ---------------------------------------------------------------------------
// Gating (y *= silu(z)) + RMSNorm over 1024 + norm_w, in place on the dir
// half of ycat (bf16).  Dir-batched: grid 16384*ndir.
// ---------------------------------------------------------------------------
__global__ __launch_bounds__(256)
void norm_k(bfu* __restrict__ ycat, const bfu* __restrict__ zx,
            const float* __restrict__ norm_w, int dir_lo)
{
  int di  = blockIdx.x >> 14;
  int dir = dir_lo + di;
  int m = blockIdx.x & 16383, tid = threadIdx.x;
  bfu* yp = ycat + (size_t)m * D_CAT + dir * 1024 + tid * 4;
  float4 y = ld4(yp);
  float4 z = ld4(zx + (size_t)m * D_PROJC + tid * 4);
  float4 g;
  g.x = y.x * silu_(z.x); g.y = y.y * silu_(z.y);
  g.z = y.z * silu_(z.z); g.w = y.w * silu_(z.w);
  float ss = g.x * g.x + g.y * g.y + g.z * g.z + g.w * g.w;
#pragma unroll
  for (int off = 32; off >= 1; off >>= 1) ss += __shfl_xor(ss, off);
  __shared__ float red[4];
  int wid = tid >> 6;
  if ((tid & 63) == 0) red[wid] = ss;
  __syncthreads();
  float tot = red[0] + red[1] + red[2] + red[3];
  float scale = rsqrtf(tot * (1.f / 1024.f) + 1e-5f);
  float4 w = *(const float4*)(norm_w + tid * 4);
  g.x *= scale * w.x; g.y *= scale * w.y; g.z *= scale * w.z; g.w *= scale * w.w;
  st4(yp, g);
}

// ---------------------------------------------------------------------------
extern "C" void kernel_launch(void* const* d_in, const int* in_sizes, int n_in,
                              void* d_out, int out_size, void* d_ws, size_t ws_size,
                              hipStream_t stream)
{
  const float* x         = (const float*)d_in[0];
  const float* in_proj_w = (const float*)d_in[1];
  const float* conv_w    = (const float*)d_in[2];
  const float* conv_b    = (const float*)d_in[3];
  const float* dt_bias   = (const float*)d_in[4];
  const float* A_log     = (const float*)d_in[5];
  const float* D_skip    = (const float*)d_in[6];
  const float* norm_w    = (const float*)d_in[7];
  const float* ssm_out_w = (const float*)d_in[8];
  const float* fuse_w    = (const float*)d_in[9];
  const float* fuse_b    = (const float*)d_in[10];
  float* out = (float*)d_out;

  const size_t ZX_E  = (size_t)M_ROWS * D_PROJC;     // 38,010,880
  const size_t XBC_E = (size_t)M_ROWS * CONV_DIMC;   // 20,971,520
  const size_t ST_E  = 33554432;
  const size_t YC_E  = (size_t)M_ROWS * D_CAT;       // 33,554,432
  const size_t AC_E  = 262144;                       // f32 elems

  // batched (ndir=2) layout needs ~353 MiB; fall back to shared buffers
  // (ndir=1, two sequential passes) if the workspace is smaller.
  size_t need2 = (ZX_E + 2 * XBC_E + 2 * ST_E + YC_E + 2 * 524288 + 1048576) * 2
               + 4 * AC_E * 4;
  const int nd = (ws_size >= need2) ? 2 : 1;

  bfu* zx     = (bfu*)d_ws;
  bfu* xBC    = zx + ZX_E;
  bfu* states = xBC + (size_t)nd * XBC_E;
  bfu* ycat   = states + (size_t)nd * ST_E;
  float* acum = (float*)(ycat + YC_E);
  float* dtg  = acum + (size_t)nd * AC_E;
  bfu* ssmTb  = (bfu*)(dtg + (size_t)nd * AC_E);     // 1024 x 512 bf16
  bfu* fuseA  = ssmTb + 524288;                      // 1024 x 512 bf16
  bfu* wcmb   = fuseA + 524288;                      // 1024 x 1024 bf16
  // transient aliases inside the states region (dead before states_mfma_k):
  bfu* xb = states;                    // 16384 x 512 bf16
  bfu* wb = states + 8388608;          // 2560  x 512 bf16 (padded for 256-tile)

  const size_t xbc_str = (nd == 2) ? XBC_E : 0;
  const size_t st_str  = (nd == 2) ? ST_E  : 0;
  const size_t ac_str  = (nd == 2) ? AC_E  : 0;

  cvt_x_k<<<8192, 256, 0, stream>>>(x, xb);
  cvt_w_k<<<1280, 256, 0, stream>>>(in_proj_w, wb);     // rows 2320..2559 zero
  transpose_k<<<2048, 256, 0, stream>>>(ssm_out_w, ssmTb);
  cvt_fuse_k<<<512, 256, 0, stream>>>(fuse_w, fuseA);

  // wcmb[(o*2+dir)][j] = sum_k fuse_w[o, dir*512+k] * ssm_out_w[k, j]
  mfma_nt<<<dim3(8, 8), 256, 0, stream>>>(
      fuseA, 512, ssmTb, 512, wcmb, 1024, 1024, 512, nullptr, 0);

  // in_proj: zx = x @ in_proj_w^T  (8-phase 256x128 pipeline, 1280 blocks
  // = exactly 5 full CU rounds at 1 block/CU)
  mfma_nt_8p<<<dim3(20, 64), 512, 0, stream>>>(
      xb, 512, wb, 512, zx, D_PROJC, D_PROJC, 512, nullptr, 0);

  for (int dl = 0; dl < 2; dl += nd) {
    conv_k<<<dim3(5, 2048 * nd), 256, 0, stream>>>(
        zx, conv_w, conv_b, xBC, xbc_str, dl);
    states_mfma_k<<<512 * nd, 256, 0, stream>>>(
        zx, xBC, xbc_str, dt_bias, A_log, acum, dtg, ac_str, states, st_str, dl);
    scan_k<<<512 * nd, 256, 0, stream>>>(states, st_str, acum, ac_str);
    y_mfma_k<<<512 * nd, 256, 0, stream>>>(
        xBC, xbc_str, states, st_str, acum, dtg, ac_str, D_skip, ycat, dl);
    norm_k<<<16384 * nd, 256, 0, stream>>>(ycat, zx, norm_w, dl);
  }

  // fused output GEMM on the 8-phase pipeline: out = ycat @ wcmb^T + fuse_b
  // (K = 2048, 16 iters; grid (4,64) = 256 blocks = exactly 1 CU round)
  mfma_nt_8p<<<dim3(4, 64), 512, 0, stream>>>(
      ycat, D_CAT, wcmb, D_CAT, out, 512, 512, D_CAT, fuse_b, 1);
}